// Round 7
// baseline (187.214 us; speedup 1.0000x reference)
//
#include <hip/hip_runtime.h>

// Batched MLP, round 7: barrier-free. No LDS, no __syncthreads.
// W fragment images live in ws (L2-resident, per-XCD via bijective swizzle);
// each wave reads its A-fragments straight from global (coalesced 1KB/inst,
// L1 x4 reuse across the block's waves). Activations stay in registers
// (permlane32_swap handoff). Waves free-run: VMEM / VALU(trans) / MFMA
// overlap across waves and layers instead of lockstep phase serialization.
// VALU diet kept: W,b pre-scaled by 2*log2(e) -> tanh = 1 trans + Newton rcp,
// cvt_pkrtz pack.

#define IND      16
#define THREADS  256
#define PARAMS   51841
#define SCALE    2.8853900817779268f   // 2*log2(e)

#define HID_STRIDE 32768                          // 4 tiles * 8 chunks * 1KB
#define WS_T     (128 * 3 * HID_STRIDE)           // 12,582,912: per-t region
#define T_STRIDE 16384
// per-t region layout:
//   +0     W0hi frag image (4KB)   : tt*1024 + r31*32 + khalf*16
//   +4096  W0lo frag image (4KB)
//   +8192  b0  scaled f32  (512B)
//   +8704  b1..b3 scaled f32 (1536B)
//   +10240 wl  f32 (512B, UNscaled)
//   +10752 bl  f32 (4B)
#define WS_XI    (WS_T + 128 * T_STRIDE)          // per-xtile x images (hi|lo)
#define WS_TOTAL (WS_XI + 32 * 8192)

typedef _Float16 f16x8 __attribute__((ext_vector_type(8)));
typedef _Float16 f16x4 __attribute__((ext_vector_type(4)));
typedef float    f32x16 __attribute__((ext_vector_type(16)));
typedef float    f32x4v __attribute__((ext_vector_type(4)));
typedef unsigned u32x2  __attribute__((ext_vector_type(2)));

union U4 { unsigned u[4]; f16x8 v; };

// Input z PRE-SCALED by 2*log2(e). tanh = sign(z)*(1 - 2t/(1+t)), t=2^(-|z|).
// 1/(1+t): quadratic seed + 1 Newton (d in [1,2], rel err ~1e-4).
__device__ __forceinline__ unsigned tanh2pk(float z0, float z1) {
    const float t0 = __builtin_amdgcn_exp2f(-__builtin_fabsf(z0));
    const float t1 = __builtin_amdgcn_exp2f(-__builtin_fabsf(z1));
    const float d0 = t0 + 1.0f, d1 = t1 + 1.0f;
    float r0 = __builtin_fmaf(d0, __builtin_fmaf(d0, 0.32302f, -1.45380f), 2.12094f);
    float r1 = __builtin_fmaf(d1, __builtin_fmaf(d1, 0.32302f, -1.45380f), 2.12094f);
    r0 = __builtin_fmaf(r0, __builtin_fmaf(-d0, r0, 1.0f), r0);
    r1 = __builtin_fmaf(r1, __builtin_fmaf(-d1, r1, 1.0f), r1);
    const float u0 = __builtin_fmaf(t0 * r0, -2.0f, 1.0f);
    const float u1 = __builtin_fmaf(t1 * r1, -2.0f, 1.0f);
    const float y0 = __builtin_copysignf(u0, z0);
    const float y1 = __builtin_copysignf(u1, z1);
    return __builtin_bit_cast(unsigned, __builtin_amdgcn_cvt_pkrtz(y0, y1));
}

#define MFMA(A, B, C) __builtin_amdgcn_mfma_f32_32x32x16_f16((A), (B), (C), 0, 0, 0)

__device__ __forceinline__ void conv8(const float* __restrict__ s, char* hidst,
                                      char* lodst, float scale) {
    float v[8];
    *reinterpret_cast<float4*>(v)     = *reinterpret_cast<const float4*>(s);
    *reinterpret_cast<float4*>(v + 4) = *reinterpret_cast<const float4*>(s + 4);
    f16x8 hi, lo;
#pragma unroll
    for (int i = 0; i < 8; ++i) {
        const float sv = v[i] * scale;
        hi[i] = (_Float16)sv;
        lo[i] = (_Float16)(sv - (float)hi[i]);
    }
    *reinterpret_cast<f16x8*>(hidst) = hi;
    *reinterpret_cast<f16x8*>(lodst) = lo;
}

// ---------------------------------------------------------------------------
// prep
//  [0,3072):     hidden W frag chunks (SCALED):
//                  (t*3+li)*32768 + ((h>>5)*8 + kc)*1024 + (kh*32+(h&31))*16
//  [3072,3136):  W0 hi/lo rows (SCALED):  WS_T + t*16384 + h*32 (lo at +4096)
//  [3136,3264):  per-t scalars: b0s, b1..3s (SCALED f32), wl, bl
//  [3264,3280):  x hi/lo rows (UNscaled):  WS_XI + xt*8192 + r*32 (lo +4096)
// ---------------------------------------------------------------------------
__global__ __launch_bounds__(256)
void prep_kernel(const float* __restrict__ theta, const float* __restrict__ xin,
                 char* __restrict__ ws)
{
    const int b = blockIdx.x, tid = threadIdx.x;
    if (b < 3072) {
        const int t = b / 24, rem = b % 24, li = rem >> 3, hblk = rem & 7;
        const int h  = hblk * 16 + (tid >> 4);
        const int kc = (tid >> 1) & 7, kh = tid & 1;
        const float* src = theta + (size_t)t * PARAMS + 2176 + li * 16512
                         + h * 128 + kc * 16 + kh * 8;
        float v[8];
        *reinterpret_cast<float4*>(v)     = *reinterpret_cast<const float4*>(src);
        *reinterpret_cast<float4*>(v + 4) = *reinterpret_cast<const float4*>(src + 4);
        f16x8 p;
#pragma unroll
        for (int i = 0; i < 8; ++i) p[i] = (_Float16)(v[i] * SCALE);
        char* img = ws + (size_t)(t * 3 + li) * HID_STRIDE;
        *reinterpret_cast<f16x8*>(img + ((h >> 5) * 8 + kc) * 1024
                                      + (kh * 32 + (h & 31)) * 16) = p;
    } else if (b < 3136) {
        const int gid = (b - 3072) * 256 + tid;
        const int t = gid >> 7, h = gid & 127;
        const float* src = theta + (size_t)t * PARAMS + h * IND;
        char* dst = ws + WS_T + (size_t)t * T_STRIDE + h * 32;
        conv8(src,     dst,      dst + 4096,      SCALE);
        conv8(src + 8, dst + 16, dst + 4096 + 16, SCALE);
    } else if (b < 3264) {
        const int t = b - 3136;
        const float* th = theta + (size_t)t * PARAMS;
        char* base = ws + WS_T + (size_t)t * T_STRIDE;
        if (tid < 128)
            *reinterpret_cast<float*>(base + 8192 + tid * 4) = SCALE * th[2048 + tid];
        for (int k = tid; k < 384; k += 256)
            *reinterpret_cast<float*>(base + 8704 + k * 4) =
                SCALE * th[2176 + (k >> 7) * 16512 + 16384 + (k & 127)];
        if (tid < 128)
            *reinterpret_cast<float*>(base + 10240 + tid * 4) = th[51712 + tid];
        if (tid == 0)
            *reinterpret_cast<float*>(base + 10752) = th[51840];
    } else {
        const int row = (b - 3264) * 256 + tid;
        const float* src = xin + (size_t)row * IND;
        char* dst = ws + WS_XI + (size_t)(row >> 7) * 8192 + (row & 127) * 32;
        conv8(src,     dst,      dst + 4096,      1.0f);   // x UNscaled
        conv8(src + 8, dst + 16, dst + 4096 + 16, 1.0f);
    }
}

// ---------------------------------------------------------------------------
// main: no LDS, no barriers.
// ---------------------------------------------------------------------------
__global__ __launch_bounds__(THREADS, 3)
void mlp_main(const char* __restrict__ ws, float* __restrict__ out)
{
    const int tid = threadIdx.x, bid = blockIdx.x;
    const int sw  = (bid & 7) * 512 + (bid >> 3);   // XCD-bijective (4096%8==0)
    const int t   = sw >> 5, xt = sw & 31;
    const int lane = tid & 63, w = tid >> 6, r31 = lane & 31, khalf = lane >> 5;
    const int bpa  = (lane ^ 32) << 2;
    (void)bpa;

    const char* wt = ws + WS_T + (size_t)t * T_STRIDE;

    f32x16 acc[4];
    f16x8  Bf[8];

    // ---- layer 0: acc = b0s + W0(hi/lo)*x(hi/lo)  (scaled domain) ----
    {
        const char* xi = ws + WS_XI + (size_t)xt * 8192;
        const int ro = r31 * 32 + khalf * 16;
        const f16x8 B0h = *reinterpret_cast<const f16x8*>(xi + w * 1024 + ro);
        const f16x8 B0l = *reinterpret_cast<const f16x8*>(xi + 4096 + w * 1024 + ro);
#pragma unroll
        for (int tt = 0; tt < 4; ++tt) {
#pragma unroll
            for (int g = 0; g < 4; ++g) {
                const f32x4v bv = *reinterpret_cast<const f32x4v*>(
                    wt + 8192 + (tt * 32 + g * 8 + khalf * 4) * 4);
                acc[tt][4 * g + 0] = bv[0]; acc[tt][4 * g + 1] = bv[1];
                acc[tt][4 * g + 2] = bv[2]; acc[tt][4 * g + 3] = bv[3];
            }
            const f16x8 Ah = *reinterpret_cast<const f16x8*>(wt + tt * 1024 + ro);
            const f16x8 Al = *reinterpret_cast<const f16x8*>(wt + 4096 + tt * 1024 + ro);
            acc[tt] = MFMA(Al, B0h, acc[tt]);
            acc[tt] = MFMA(Ah, B0l, acc[tt]);
            acc[tt] = MFMA(Ah, B0h, acc[tt]);
        }
    }

    // tanh+pack all 4 tiles -> Bf[0..8) (permlane32_swap half-exchange)
    auto activate_pack = [&]() {
#pragma unroll
        for (int tt = 0; tt < 4; ++tt) {
            unsigned P0[4], P1[4];
#pragma unroll
            for (int g = 0; g < 4; ++g) {
                P0[g] = tanh2pk(acc[tt][4 * g + 0], acc[tt][4 * g + 1]);
                P1[g] = tanh2pk(acc[tt][4 * g + 2], acc[tt][4 * g + 3]);
            }
#pragma unroll
            for (int j = 0; j < 2; ++j) {
#if __has_builtin(__builtin_amdgcn_permlane32_swap)
                const u32x2 r0 = __builtin_amdgcn_permlane32_swap(
                    P0[2 * j], P0[2 * j + 1], false, false);
                const u32x2 r1 = __builtin_amdgcn_permlane32_swap(
                    P1[2 * j], P1[2 * j + 1], false, false);
                U4 u;
                u.u[0] = r0[0]; u.u[1] = r1[0]; u.u[2] = r0[1]; u.u[3] = r1[1];
#else
                const unsigned s0 = khalf ? P0[2 * j] : P0[2 * j + 1];
                const unsigned s1 = khalf ? P1[2 * j] : P1[2 * j + 1];
                const unsigned q0 = (unsigned)__builtin_amdgcn_ds_bpermute(bpa, (int)s0);
                const unsigned q1 = (unsigned)__builtin_amdgcn_ds_bpermute(bpa, (int)s1);
                U4 u;
                u.u[0] = khalf ? q0 : P0[2 * j];
                u.u[1] = khalf ? q1 : P1[2 * j];
                u.u[2] = khalf ? P0[2 * j + 1] : q0;
                u.u[3] = khalf ? P1[2 * j + 1] : q1;
#endif
                Bf[2 * tt + j] = u.v;
            }
        }
    };
    activate_pack();

    // ---- hidden layers 1..3: A-frags straight from global (L1/L2) ----
#pragma unroll
    for (int l = 0; l < 3; ++l) {
        const char* img  = ws + (size_t)(t * 3 + l) * HID_STRIDE;
        const char* bias = wt + 8704 + l * 512;
#pragma unroll
        for (int tt = 0; tt < 4; ++tt) {
#pragma unroll
            for (int g = 0; g < 4; ++g) {
                const f32x4v bv = *reinterpret_cast<const f32x4v*>(
                    bias + (tt * 32 + g * 8 + khalf * 4) * 4);
                acc[tt][4 * g + 0] = bv[0]; acc[tt][4 * g + 1] = bv[1];
                acc[tt][4 * g + 2] = bv[2]; acc[tt][4 * g + 3] = bv[3];
            }
        }
#pragma unroll
        for (int kc = 0; kc < 8; ++kc)
#pragma unroll
            for (int tt = 0; tt < 4; ++tt) {
                const f16x8 av = *reinterpret_cast<const f16x8*>(
                    img + (tt * 8 + kc) * 1024 + lane * 16);
                acc[tt] = MFMA(av, Bf[kc], acc[tt]);
            }
        activate_pack();
    }

    // ---- final: out[x] = wl . h4 + bl  (f32 fma + half-exchange reduce) ----
    float s = 0.0f;
#pragma unroll
    for (int kc = 0; kc < 8; ++kc) {
        // Bf[kc].u[0..1] hold h = 16kc + khalf*... -- instead reduce from acc:
        // use the packed post-tanh values via fmaf on the pre-pack floats is
        // gone; recompute from Bf halves is messy -> use acc path:
        // (acc still holds pre-activation z; tanh(z) needed)
        (void)kc;
    }
    {
        const char* wl = wt + 10240;
#pragma unroll
        for (int tt = 0; tt < 4; ++tt)
#pragma unroll
            for (int g = 0; g < 4; ++g) {
                const f32x4v wv = *reinterpret_cast<const f32x4v*>(
                    wl + (tt * 32 + g * 8 + khalf * 4) * 4);
                const float z0 = acc[tt][4 * g + 0], z1 = acc[tt][4 * g + 1];
                const float z2 = acc[tt][4 * g + 2], z3 = acc[tt][4 * g + 3];
                // tanh via same 1-trans formula, f32 result
                const float e0 = __builtin_amdgcn_exp2f(-__builtin_fabsf(z0));
                const float e1 = __builtin_amdgcn_exp2f(-__builtin_fabsf(z1));
                const float e2 = __builtin_amdgcn_exp2f(-__builtin_fabsf(z2));
                const float e3 = __builtin_amdgcn_exp2f(-__builtin_fabsf(z3));
                const float y0 = __builtin_copysignf(
                    __builtin_fmaf(e0 * __builtin_amdgcn_rcpf(1.0f + e0), -2.0f, 1.0f), z0);
                const float y1 = __builtin_copysignf(
                    __builtin_fmaf(e1 * __builtin_amdgcn_rcpf(1.0f + e1), -2.0f, 1.0f), z1);
                const float y2 = __builtin_copysignf(
                    __builtin_fmaf(e2 * __builtin_amdgcn_rcpf(1.0f + e2), -2.0f, 1.0f), z2);
                const float y3 = __builtin_copysignf(
                    __builtin_fmaf(e3 * __builtin_amdgcn_rcpf(1.0f + e3), -2.0f, 1.0f), z3);
                s = __builtin_fmaf(y0, wv[0], s);
                s = __builtin_fmaf(y1, wv[1], s);
                s = __builtin_fmaf(y2, wv[2], s);
                s = __builtin_fmaf(y3, wv[3], s);
            }
    }
    const float sp = __builtin_bit_cast(float,
        __builtin_amdgcn_ds_bpermute(bpa, __builtin_bit_cast(int, s)));
    const float res = s + sp + *reinterpret_cast<const float*>(wt + 10752);
    if (!khalf) out[(size_t)t * 4096 + xt * 128 + w * 32 + r31] = res;
}

// ---------------------------------------------------------------------------
// Fallback (self-contained, known-good round-1 kernel) if ws is too small.
// ---------------------------------------------------------------------------
__global__ __launch_bounds__(THREADS, 1)
void mlp_kernel_fb(const float* __restrict__ xin,
                   const float* __restrict__ theta,
                   float* __restrict__ out)
{
    __shared__ __align__(16) _Float16 sH   [128 * 128];
    __shared__ __align__(16) _Float16 sWhi [128 * 128];
    __shared__ __align__(16) _Float16 sWlo [128 * 128];
    __shared__ __align__(16) _Float16 sX0hi[128 * IND];
    __shared__ __align__(16) _Float16 sX0lo[128 * IND];
    __shared__ __align__(16) _Float16 sW0hi[128 * IND];
    __shared__ __align__(16) _Float16 sW0lo[128 * IND];
    __shared__ float sB[2][128];
    __shared__ float sWl[129];

    const int tid = threadIdx.x;
    const int bid = blockIdx.x;
    const int sw  = (bid & 7) * 512 + (bid >> 3);
    const int t   = sw >> 5;
    const int xt  = sw & 31;
    const float* __restrict__ th = theta + (size_t)t * PARAMS;
    const float* __restrict__ xg = xin   + (size_t)xt * (128 * IND);

#pragma unroll
    for (int j = 0; j < 2; ++j) {
        const int flat = j * 1024 + tid * 4;
        const float4 v = *reinterpret_cast<const float4*>(xg + flat);
        _Float16 h0 = (_Float16)v.x, h1 = (_Float16)v.y, h2 = (_Float16)v.z, h3 = (_Float16)v.w;
        f16x4 ph = {h0, h1, h2, h3};
        f16x4 pl = {(_Float16)(v.x - (float)h0), (_Float16)(v.y - (float)h1),
                    (_Float16)(v.z - (float)h2), (_Float16)(v.w - (float)h3)};
        *reinterpret_cast<f16x4*>(&sX0hi[flat]) = ph;
        *reinterpret_cast<f16x4*>(&sX0lo[flat]) = pl;
    }
#pragma unroll
    for (int j = 0; j < 2; ++j) {
        const int flat = j * 1024 + tid * 4;
        const float a0 = th[flat], a1 = th[flat + 1], a2 = th[flat + 2], a3 = th[flat + 3];
        _Float16 h0 = (_Float16)a0, h1 = (_Float16)a1, h2 = (_Float16)a2, h3 = (_Float16)a3;
        f16x4 ph = {h0, h1, h2, h3};
        f16x4 pl = {(_Float16)(a0 - (float)h0), (_Float16)(a1 - (float)h1),
                    (_Float16)(a2 - (float)h2), (_Float16)(a3 - (float)h3)};
        *reinterpret_cast<f16x4*>(&sW0hi[flat]) = ph;
        *reinterpret_cast<f16x4*>(&sW0lo[flat]) = pl;
    }
    if (tid < 128) sB[0][tid] = th[IND * 128 + tid];
    __syncthreads();

    const int lane  = tid & 63;
    const int w     = tid >> 6;
    const int r31   = lane & 31;
    const int khalf = lane >> 5;
    const int hb    = (w >> 1) * 64;
    const int xb    = (w & 1) * 64;
    const int hA0 = hb + r31,  hA1 = hb + 32 + r31;
    const int xB0 = xb + r31,  xB1 = xb + 32 + r31;
    const int swzA0 = (hA0 & 15) << 4, swzA1 = (hA1 & 15) << 4;
    const int swzB0 = (xB0 & 15) << 4, swzB1 = (xB1 & 15) << 4;

    f32x16 acc[2][2];

    {
        const int kb = khalf * 16;
        f16x8 ah[2], al[2], bh[2], bl[2];
        ah[0] = *reinterpret_cast<const f16x8*>((const char*)sW0hi + hA0 * 32 + kb);
        ah[1] = *reinterpret_cast<const f16x8*>((const char*)sW0hi + hA1 * 32 + kb);
        al[0] = *reinterpret_cast<const f16x8*>((const char*)sW0lo + hA0 * 32 + kb);
        al[1] = *reinterpret_cast<const f16x8*>((const char*)sW0lo + hA1 * 32 + kb);
        bh[0] = *reinterpret_cast<const f16x8*>((const char*)sX0hi + xB0 * 32 + kb);
        bh[1] = *reinterpret_cast<const f16x8*>((const char*)sX0hi + xB1 * 32 + kb);
        bl[0] = *reinterpret_cast<const f16x8*>((const char*)sX0lo + xB0 * 32 + kb);
        bl[1] = *reinterpret_cast<const f16x8*>((const char*)sX0lo + xB1 * 32 + kb);
#pragma unroll
        for (int tt = 0; tt < 2; ++tt)
#pragma unroll
            for (int tx = 0; tx < 2; ++tx) {
                f32x16 a;
#pragma unroll
                for (int i = 0; i < 16; ++i) a[i] = 0.0f;
                a = MFMA(al[tt], bh[tx], a);
                a = MFMA(ah[tt], bl[tx], a);
                a = MFMA(ah[tt], bh[tx], a);
                acc[tt][tx] = a;
            }
    }

    auto epilogue = [&](const float* __restrict__ bb) {
#pragma unroll
        for (int tt = 0; tt < 2; ++tt)
#pragma unroll
            for (int tx = 0; tx < 2; ++tx) {
                const int xw  = xb + tx * 32 + r31;
                const int swz = (xw & 15) << 4;
#pragma unroll
                for (int g = 0; g < 4; ++g) {
                    const int hbase = hb + tt * 32 + g * 8 + khalf * 4;
                    f16x4 pk;
#pragma unroll
                    for (int q = 0; q < 4; ++q) {
                        const float v = acc[tt][tx][g * 4 + q] + bb[hbase + q];
                        pk[q] = (_Float16)(1.0f - 2.0f * __builtin_amdgcn_rcpf(
                            __builtin_amdgcn_exp2f(v * 2.8853900817779268f) + 1.0f));
                    }
                    *reinterpret_cast<f16x4*>((char*)sH + xw * 256 + ((hbase * 2) ^ swz)) = pk;
                }
            }
    };

    for (int l = 0; l < 3; ++l) {
        __syncthreads();
        const float* __restrict__ wsrc = th + 2176 + l * 16512;
#pragma unroll
        for (int j = 0; j < 16; ++j) {
            const int flat = j * 1024 + tid * 4;
            const int hrow = flat >> 7;
            const int o    = flat & 127;
            const float a0 = wsrc[flat], a1 = wsrc[flat + 1], a2 = wsrc[flat + 2], a3 = wsrc[flat + 3];
            _Float16 h0 = (_Float16)a0, h1 = (_Float16)a1, h2 = (_Float16)a2, h3 = (_Float16)a3;
            f16x4 ph = {h0, h1, h2, h3};
            f16x4 pl = {(_Float16)(a0 - (float)h0), (_Float16)(a1 - (float)h1),
                        (_Float16)(a2 - (float)h2), (_Float16)(a3 - (float)h3)};
            const int boff = hrow * 256 + ((o * 2) ^ ((hrow & 15) << 4));
            *reinterpret_cast<f16x4*>((char*)sWhi + boff) = ph;
            *reinterpret_cast<f16x4*>((char*)sWlo + boff) = pl;
        }
        if (tid < 128) sB[(l + 1) & 1][tid] = wsrc[128 * 128 + tid];
        if (l == 2) {
            if (tid < 128) sWl[tid] = th[51712 + tid];
            if (tid == 128) sWl[128] = th[51840];
        }

        epilogue(sB[l & 1]);
        __syncthreads();

#pragma unroll
        for (int tt = 0; tt < 2; ++tt)
#pragma unroll
            for (int tx = 0; tx < 2; ++tx)
#pragma unroll
                for (int i = 0; i < 16; ++i) acc[tt][tx][i] = 0.0f;
#pragma unroll
        for (int kc = 0; kc < 8; ++kc) {
            const int kb = kc * 32 + khalf * 16;
            f16x8 ah[2], al[2], bv[2];
            ah[0] = *reinterpret_cast<const f16x8*>((const char*)sWhi + hA0 * 256 + (kb ^ swzA0));
            ah[1] = *reinterpret_cast<const f16x8*>((const char*)sWhi + hA1 * 256 + (kb ^ swzA1));
            al[0] = *reinterpret_cast<const f16x8*>((const char*)sWlo + hA0 * 256 + (kb ^ swzA0));
            al[1] = *reinterpret_cast<const f16x8*>((const char*)sWlo + hA1 * 256 + (kb ^ swzA1));
            bv[0] = *reinterpret_cast<const f16x8*>((const char*)sH   + xB0 * 256 + (kb ^ swzB0));
            bv[1] = *reinterpret_cast<const f16x8*>((const char*)sH   + xB1 * 256 + (kb ^ swzB1));
#pragma unroll
            for (int tt = 0; tt < 2; ++tt)
#pragma unroll
                for (int tx = 0; tx < 2; ++tx) {
                    acc[tt][tx] = MFMA(al[tt], bv[tx], acc[tt][tx]);
                    acc[tt][tx] = MFMA(ah[tt], bv[tx], acc[tt][tx]);
                }
        }
    }

    __syncthreads();
    epilogue(sB[1]);
    __syncthreads();

    if (tid < 128) {
        const int r   = tid;
        const int swz = (r & 15) << 4;
        float s = 0.0f;
#pragma unroll
        for (int c = 0; c < 16; ++c) {
            const int hc = (c + r) & 15;
            const f16x8 hv = *reinterpret_cast<const f16x8*>(
                (const char*)sH + r * 256 + ((hc * 16) ^ swz));
#pragma unroll
            for (int q = 0; q < 8; ++q) s += (float)hv[q] * sWl[hc * 8 + q];
        }
        out[(size_t)t * 4096 + (size_t)xt * 128 + r] = s + sWl[128];
    }
}

extern "C" void kernel_launch(void* const* d_in, const int* in_sizes, int n_in,
                              void* d_out, int out_size, void* d_ws, size_t ws_size,
                              hipStream_t stream)
{
    const float* x     = (const float*)d_in[0];
    const float* theta = (const float*)d_in[1];
    float* out = (float*)d_out;

    if (ws_size >= (size_t)WS_TOTAL) {
        prep_kernel<<<dim3(3280), dim3(256), 0, stream>>>(theta, x, (char*)d_ws);
        mlp_main<<<dim3(4096), dim3(THREADS), 0, stream>>>((const char*)d_ws, out);
    } else {
        mlp_kernel_fb<<<dim3(4096), dim3(THREADS), 0, stream>>>(x, theta, out);
    }
}

// Round 8
// 116.996 us; speedup vs baseline: 1.6002x; 1.6002x over previous
//
#include <hip/hip_runtime.h>

// Batched MLP, round 8: round-4 structure (best measured: 105.2us) with the
// r6/r7-validated VALU diet applied in isolation.
// - One wave owns 128h x 32x; activations in registers (permlane32_swap).
// - LDS: current-W image (32KB, fragment-linear via global_load_lds) + scaled
//   bias/wl tables. 4 blocks/CU.
// - W0..W3, b0..b3 pre-scaled by 2*log2(e) in prep -> tanh is 1 trans op
//   (exp2 with free -|z| modifiers) + Newton reciprocal + cvt_pkrtz pack.

#define IND      16
#define THREADS  256
#define PARAMS   51841
#define SCALE    2.8853900817779268f   // 2*log2(e)

#define WS_W0    12582912                  // 128*3*32768 hidden-W frag images
#define WS_SC    (WS_W0 + 128 * 8192)      // + per-t W0 images (hi|lo)
#define WS_X     (WS_SC + 128 * 4096)      // + per-t scalars (4KB each)
#define WS_TOTAL (WS_X + 32 * 8192)        // + per-xtile x images = 14,417,920

// per-t scalar block (f32): +0 b0s(128) | +512B b1..3s(384) | +2048B wl(128) | +2560B bl(1)

#define LDS_B    32768                      // staged b1..3s (1536B)
#define LDS_WL   (32768 + 1536)             // wl (512B) + bl (4B)
#define LDS_SZ   (32768 + 1536 + 520)

typedef _Float16 f16x8 __attribute__((ext_vector_type(8)));
typedef _Float16 f16x4 __attribute__((ext_vector_type(4)));
typedef float    f32x16 __attribute__((ext_vector_type(16)));
typedef float    f32x4v __attribute__((ext_vector_type(4)));
typedef unsigned u32x2  __attribute__((ext_vector_type(2)));

union U4 { unsigned u[4]; f16x8 v; };

__device__ __forceinline__ f32x16 zero16() {
    f32x16 z;
#pragma unroll
    for (int i = 0; i < 16; ++i) z[i] = 0.0f;
    return z;
}

// z PRE-SCALED by 2*log2(e). tanh = sign(z)*(1 - 2t/(1+t)), t = 2^(-|z|).
// 1/(1+t): quadratic seed + 1 Newton (d in [1,2], rel err ~1e-4).
// Validated r6/r7: absmax 0.5625 (same as exact rcp).
__device__ __forceinline__ unsigned tanh2pk(float z0, float z1) {
    const float t0 = __builtin_amdgcn_exp2f(-__builtin_fabsf(z0));
    const float t1 = __builtin_amdgcn_exp2f(-__builtin_fabsf(z1));
    const float d0 = t0 + 1.0f, d1 = t1 + 1.0f;
    float r0 = __builtin_fmaf(d0, __builtin_fmaf(d0, 0.32302f, -1.45380f), 2.12094f);
    float r1 = __builtin_fmaf(d1, __builtin_fmaf(d1, 0.32302f, -1.45380f), 2.12094f);
    r0 = __builtin_fmaf(r0, __builtin_fmaf(-d0, r0, 1.0f), r0);
    r1 = __builtin_fmaf(r1, __builtin_fmaf(-d1, r1, 1.0f), r1);
    const float u0 = __builtin_fmaf(t0 * r0, -2.0f, 1.0f);
    const float u1 = __builtin_fmaf(t1 * r1, -2.0f, 1.0f);
    const float y0 = __builtin_copysignf(u0, z0);
    const float y1 = __builtin_copysignf(u1, z1);
    return __builtin_bit_cast(unsigned, __builtin_amdgcn_cvt_pkrtz(y0, y1));
}

#define MFMA(A, B, C) __builtin_amdgcn_mfma_f32_32x32x16_f16((A), (B), (C), 0, 0, 0)

__device__ __forceinline__ void gload16(const void* g, void* l) {
    __builtin_amdgcn_global_load_lds(
        (const __attribute__((address_space(1))) void*)g,
        (__attribute__((address_space(3))) void*)l, 16, 0, 0);
}

__device__ __forceinline__ void conv8(const float* __restrict__ s, char* hidst,
                                      char* lodst, float scale) {
    float v[8];
    *reinterpret_cast<float4*>(v)     = *reinterpret_cast<const float4*>(s);
    *reinterpret_cast<float4*>(v + 4) = *reinterpret_cast<const float4*>(s + 4);
    f16x8 hi, lo;
#pragma unroll
    for (int i = 0; i < 8; ++i) {
        const float sv = v[i] * scale;
        hi[i] = (_Float16)sv;
        lo[i] = (_Float16)(sv - (float)hi[i]);
    }
    *reinterpret_cast<f16x8*>(hidst) = hi;
    *reinterpret_cast<f16x8*>(lodst) = lo;
}

// ---------------------------------------------------------------------------
// prep:
//  [0,3072):     hidden W frag chunks (SCALED):
//                  (t*3+li)*32768 + ((h>>5)*8+kc)*1024 + (kh*32+(h&31))*16
//  [3072,3136):  W0 hi/lo rows (SCALED):  WS_SC? no -> WS_W0 + t*8192 + h*32
//  [3136,3264):  per-t scalar block (SCALED biases; wl/bl unscaled)
//  [3264,3280):  x hi/lo rows (UNscaled): WS_X + xt*8192 + r*32 (lo +4096)
// ---------------------------------------------------------------------------
__global__ __launch_bounds__(256)
void prep_kernel(const float* __restrict__ theta, const float* __restrict__ xin,
                 char* __restrict__ ws)
{
    const int b = blockIdx.x, tid = threadIdx.x;
    if (b < 3072) {
        const int t = b / 24, rem = b % 24, li = rem >> 3, hblk = rem & 7;
        const int h  = hblk * 16 + (tid >> 4);
        const int kc = (tid >> 1) & 7, kh = tid & 1;
        const float* src = theta + (size_t)t * PARAMS + 2176 + li * 16512
                         + h * 128 + kc * 16 + kh * 8;
        float v[8];
        *reinterpret_cast<float4*>(v)     = *reinterpret_cast<const float4*>(src);
        *reinterpret_cast<float4*>(v + 4) = *reinterpret_cast<const float4*>(src + 4);
        f16x8 p;
#pragma unroll
        for (int i = 0; i < 8; ++i) p[i] = (_Float16)(v[i] * SCALE);
        char* img = ws + ((size_t)(t * 3 + li) << 15);
        *reinterpret_cast<f16x8*>(img + ((h >> 5) * 8 + kc) * 1024
                                      + (kh * 32 + (h & 31)) * 16) = p;
    } else if (b < 3136) {
        const int gid = (b - 3072) * 256 + tid;
        const int t = gid >> 7, h = gid & 127;
        const float* src = theta + (size_t)t * PARAMS + h * IND;
        char* dst = ws + WS_W0 + (size_t)t * 8192 + h * 32;
        conv8(src,     dst,      dst + 4096,      SCALE);
        conv8(src + 8, dst + 16, dst + 4096 + 16, SCALE);
    } else if (b < 3264) {
        const int t = b - 3136;
        const float* th = theta + (size_t)t * PARAMS;
        float* base = reinterpret_cast<float*>(ws + WS_SC + (size_t)t * 4096);
        if (tid < 128) base[tid] = SCALE * th[2048 + tid];                 // b0s
        for (int k = tid; k < 384; k += 256)                               // b1..3s
            base[128 + k] = SCALE * th[2176 + (k >> 7) * 16512 + 16384 + (k & 127)];
        if (tid < 128) base[512 + tid] = th[51712 + tid];                  // wl
        if (tid == 0)  base[640] = th[51840];                              // bl
    } else {
        const int row = (b - 3264) * 256 + tid;
        const float* src = xin + (size_t)row * IND;
        char* dst = ws + WS_X + (size_t)(row >> 7) * 8192 + (row & 127) * 32;
        conv8(src,     dst,      dst + 4096,      1.0f);   // x UNscaled
        conv8(src + 8, dst + 16, dst + 4096 + 16, 1.0f);
    }
}

// ---------------------------------------------------------------------------
// main (round-4 structure)
// ---------------------------------------------------------------------------
__global__ __launch_bounds__(THREADS, 4)
void mlp_main(const char* __restrict__ ws, float* __restrict__ out)
{
    __shared__ __align__(16) char sL[LDS_SZ];

    const int tid = threadIdx.x, bid = blockIdx.x;
    const int sw  = (bid & 7) * 512 + (bid >> 3);   // XCD-bijective (4096%8==0)
    const int t   = sw >> 5, xt = sw & 31;
    const int lane = tid & 63, w = tid >> 6, r31 = lane & 31, khalf = lane >> 5;
    const int bpa  = (lane ^ 32) << 2;
    (void)bpa;

    const float* __restrict__ wsc = reinterpret_cast<const float*>(
        ws + WS_SC + (size_t)t * 4096);

    // ---- stage W1 (async, fragment-linear -> linear LDS) ----
    {
        const char* img = ws + ((size_t)(t * 3) << 15);
#pragma unroll
        for (int c = 0; c < 8; ++c)
            gload16(img + (w + c * 4) * 1024 + lane * 16, sL + (w + c * 4) * 1024);
    }
    // ---- stage scaled b1..3 + wl + bl (straight f32 copy from ws) ----
    for (int k = tid; k < 513; k += THREADS)
        *reinterpret_cast<float*>(sL + LDS_B + k * 4) = wsc[128 + k];

    // ---- layer 0: acc = b0s; acc += W0(hi/lo) * x(hi/lo), K=16 (scaled) ----
    f32x16 acc[4];
    {
        const char* w0i = ws + WS_W0 + (size_t)t  * 8192;
        const char* xi  = ws + WS_X  + (size_t)xt * 8192;
        const int ro = r31 * 32 + khalf * 16;
        const f16x8 B0h = *reinterpret_cast<const f16x8*>(xi + w * 1024 + ro);
        const f16x8 B0l = *reinterpret_cast<const f16x8*>(xi + 4096 + w * 1024 + ro);
#pragma unroll
        for (int tt = 0; tt < 4; ++tt) {
#pragma unroll
            for (int g = 0; g < 4; ++g) {
                const f32x4v bv = *reinterpret_cast<const f32x4v*>(
                    wsc + tt * 32 + g * 8 + khalf * 4);
                acc[tt][4 * g + 0] = bv[0]; acc[tt][4 * g + 1] = bv[1];
                acc[tt][4 * g + 2] = bv[2]; acc[tt][4 * g + 3] = bv[3];
            }
            const f16x8 Ah = *reinterpret_cast<const f16x8*>(w0i + tt * 1024 + ro);
            const f16x8 Al = *reinterpret_cast<const f16x8*>(w0i + 4096 + tt * 1024 + ro);
            acc[tt] = MFMA(Al, B0h, acc[tt]);
            acc[tt] = MFMA(Ah, B0l, acc[tt]);
            acc[tt] = MFMA(Ah, B0h, acc[tt]);
        }
    }

    f16x8 Bf[8];
    // tanh(acc) -> f16 pack (RTZ) -> permlane32_swap assembles next-layer
    // B-frags (tt-outer fusion keeps transients to 8 regs; round-4 layout).
    auto activate_pack = [&]() {
#pragma unroll
        for (int tt = 0; tt < 4; ++tt) {
            unsigned P0[4], P1[4];
#pragma unroll
            for (int g = 0; g < 4; ++g) {
                P0[g] = tanh2pk(acc[tt][4 * g + 0], acc[tt][4 * g + 1]);
                P1[g] = tanh2pk(acc[tt][4 * g + 2], acc[tt][4 * g + 3]);
            }
#pragma unroll
            for (int j = 0; j < 2; ++j) {        // kc = 2*tt + j
#if __has_builtin(__builtin_amdgcn_permlane32_swap)
                const u32x2 r0 = __builtin_amdgcn_permlane32_swap(
                    P0[2 * j], P0[2 * j + 1], false, false);
                const u32x2 r1 = __builtin_amdgcn_permlane32_swap(
                    P1[2 * j], P1[2 * j + 1], false, false);
                U4 u;
                u.u[0] = r0[0]; u.u[1] = r1[0]; u.u[2] = r0[1]; u.u[3] = r1[1];
#else
                const unsigned s0 = khalf ? P0[2 * j] : P0[2 * j + 1];
                const unsigned s1 = khalf ? P1[2 * j] : P1[2 * j + 1];
                const unsigned q0 = (unsigned)__builtin_amdgcn_ds_bpermute(bpa, (int)s0);
                const unsigned q1 = (unsigned)__builtin_amdgcn_ds_bpermute(bpa, (int)s1);
                U4 u;
                u.u[0] = khalf ? q0 : P0[2 * j];
                u.u[1] = khalf ? q1 : P1[2 * j];
                u.u[2] = khalf ? P0[2 * j + 1] : q0;
                u.u[3] = khalf ? P1[2 * j + 1] : q1;
#endif
                Bf[2 * tt + j] = u.v;
            }
        }
    };
    activate_pack();
    __syncthreads();            // W1 staged + scalar tables visible

    // ---- hidden layers 1..3 ----
#pragma unroll
    for (int l = 1; l <= 3; ++l) {
        __builtin_amdgcn_s_setprio(1);
#pragma unroll
        for (int tt = 0; tt < 4; ++tt) {
            // acc = scaled bias_l (broadcast ds_read_b128, conflict-free)
#pragma unroll
            for (int g = 0; g < 4; ++g) {
                const f32x4v bv = *reinterpret_cast<const f32x4v*>(
                    sL + LDS_B + (l - 1) * 512 + (tt * 32 + g * 8) * 4 + khalf * 16);
                acc[tt][4 * g + 0] = bv[0]; acc[tt][4 * g + 1] = bv[1];
                acc[tt][4 * g + 2] = bv[2]; acc[tt][4 * g + 3] = bv[3];
            }
            // A-reads: one addr reg (lane*16) + immediate offsets; conflict-free.
#pragma unroll
            for (int kc = 0; kc < 8; ++kc) {
                const f16x8 a = *reinterpret_cast<const f16x8*>(
                    sL + (tt * 8 + kc) * 1024 + lane * 16);
                acc[tt] = MFMA(a, Bf[kc], acc[tt]);
            }
        }
        __builtin_amdgcn_s_setprio(0);
        if (l < 3) {
            __syncthreads();    // all waves done reading W_l
            const char* img = ws + ((size_t)(t * 3 + l) << 15);
#pragma unroll
            for (int c = 0; c < 8; ++c)
                gload16(img + (w + c * 4) * 1024 + lane * 16, sL + (w + c * 4) * 1024);
            activate_pack();    // long VALU phase hides the stage latency
            __syncthreads();    // W_{l+1} visible (barrier drains vmcnt)
        }
    }

    // ---- final: out[x] = wl . tanh(acc_scaled) + bl  (f32) ----
    float s = 0.0f;
#pragma unroll
    for (int tt = 0; tt < 4; ++tt)
#pragma unroll
        for (int g = 0; g < 4; ++g) {
            const f32x4v wv = *reinterpret_cast<const f32x4v*>(
                sL + LDS_WL + (tt * 32 + g * 8) * 4 + khalf * 16);
#pragma unroll
            for (int q = 0; q < 4; ++q) {
                const float z = acc[tt][4 * g + q];
                const float e = __builtin_amdgcn_exp2f(-__builtin_fabsf(z));
                const float y = __builtin_copysignf(
                    __builtin_fmaf(e * __builtin_amdgcn_rcpf(1.0f + e), -2.0f, 1.0f), z);
                s = __builtin_fmaf(y, wv[q], s);
            }
        }
    const float sp = __builtin_bit_cast(float,
        __builtin_amdgcn_ds_bpermute(bpa, __builtin_bit_cast(int, s)));
    const float res = s + sp + *reinterpret_cast<const float*>(sL + LDS_WL + 512);
    if (!khalf) out[(size_t)t * 4096 + xt * 128 + w * 32 + r31] = res;
}

// ---------------------------------------------------------------------------
// Fallback (self-contained, known-good round-1 kernel) if ws is too small.
// ---------------------------------------------------------------------------
__global__ __launch_bounds__(THREADS, 1)
void mlp_kernel_fb(const float* __restrict__ xin,
                   const float* __restrict__ theta,
                   float* __restrict__ out)
{
    __shared__ __align__(16) _Float16 sH   [128 * 128];
    __shared__ __align__(16) _Float16 sWhi [128 * 128];
    __shared__ __align__(16) _Float16 sWlo [128 * 128];
    __shared__ __align__(16) _Float16 sX0hi[128 * IND];
    __shared__ __align__(16) _Float16 sX0lo[128 * IND];
    __shared__ __align__(16) _Float16 sW0hi[128 * IND];
    __shared__ __align__(16) _Float16 sW0lo[128 * IND];
    __shared__ float sB[2][128];
    __shared__ float sWl[129];

    const int tid = threadIdx.x;
    const int bid = blockIdx.x;
    const int sw  = (bid & 7) * 512 + (bid >> 3);
    const int t   = sw >> 5;
    const int xt  = sw & 31;
    const float* __restrict__ th = theta + (size_t)t * PARAMS;
    const float* __restrict__ xg = xin   + (size_t)xt * (128 * IND);

#pragma unroll
    for (int j = 0; j < 2; ++j) {
        const int flat = j * 1024 + tid * 4;
        const float4 v = *reinterpret_cast<const float4*>(xg + flat);
        _Float16 h0 = (_Float16)v.x, h1 = (_Float16)v.y, h2 = (_Float16)v.z, h3 = (_Float16)v.w;
        f16x4 ph = {h0, h1, h2, h3};
        f16x4 pl = {(_Float16)(v.x - (float)h0), (_Float16)(v.y - (float)h1),
                    (_Float16)(v.z - (float)h2), (_Float16)(v.w - (float)h3)};
        *reinterpret_cast<f16x4*>(&sX0hi[flat]) = ph;
        *reinterpret_cast<f16x4*>(&sX0lo[flat]) = pl;
    }
#pragma unroll
    for (int j = 0; j < 2; ++j) {
        const int flat = j * 1024 + tid * 4;
        const float a0 = th[flat], a1 = th[flat + 1], a2 = th[flat + 2], a3 = th[flat + 3];
        _Float16 h0 = (_Float16)a0, h1 = (_Float16)a1, h2 = (_Float16)a2, h3 = (_Float16)a3;
        f16x4 ph = {h0, h1, h2, h3};
        f16x4 pl = {(_Float16)(a0 - (float)h0), (_Float16)(a1 - (float)h1),
                    (_Float16)(a2 - (float)h2), (_Float16)(a3 - (float)h3)};
        *reinterpret_cast<f16x4*>(&sW0hi[flat]) = ph;
        *reinterpret_cast<f16x4*>(&sW0lo[flat]) = pl;
    }
    if (tid < 128) sB[0][tid] = th[IND * 128 + tid];
    __syncthreads();

    const int lane  = tid & 63;
    const int w     = tid >> 6;
    const int r31   = lane & 31;
    const int khalf = lane >> 5;
    const int hb    = (w >> 1) * 64;
    const int xb    = (w & 1) * 64;
    const int hA0 = hb + r31,  hA1 = hb + 32 + r31;
    const int xB0 = xb + r31,  xB1 = xb + 32 + r31;
    const int swzA0 = (hA0 & 15) << 4, swzA1 = (hA1 & 15) << 4;
    const int swzB0 = (xB0 & 15) << 4, swzB1 = (xB1 & 15) << 4;

    f32x16 acc[2][2];

    {
        const int kb = khalf * 16;
        f16x8 ah[2], al[2], bh[2], bl[2];
        ah[0] = *reinterpret_cast<const f16x8*>((const char*)sW0hi + hA0 * 32 + kb);
        ah[1] = *reinterpret_cast<const f16x8*>((const char*)sW0hi + hA1 * 32 + kb);
        al[0] = *reinterpret_cast<const f16x8*>((const char*)sW0lo + hA0 * 32 + kb);
        al[1] = *reinterpret_cast<const f16x8*>((const char*)sW0lo + hA1 * 32 + kb);
        bh[0] = *reinterpret_cast<const f16x8*>((const char*)sX0hi + xB0 * 32 + kb);
        bh[1] = *reinterpret_cast<const f16x8*>((const char*)sX0hi + xB1 * 32 + kb);
        bl[0] = *reinterpret_cast<const f16x8*>((const char*)sX0lo + xB0 * 32 + kb);
        bl[1] = *reinterpret_cast<const f16x8*>((const char*)sX0lo + xB1 * 32 + kb);
#pragma unroll
        for (int tt = 0; tt < 2; ++tt)
#pragma unroll
            for (int tx = 0; tx < 2; ++tx) {
                f32x16 a;
#pragma unroll
                for (int i = 0; i < 16; ++i) a[i] = 0.0f;
                a = MFMA(al[tt], bh[tx], a);
                a = MFMA(ah[tt], bl[tx], a);
                a = MFMA(ah[tt], bh[tx], a);
                acc[tt][tx] = a;
            }
    }

    auto epilogue = [&](const float* __restrict__ bb) {
#pragma unroll
        for (int tt = 0; tt < 2; ++tt)
#pragma unroll
            for (int tx = 0; tx < 2; ++tx) {
                const int xw  = xb + tx * 32 + r31;
                const int swz = (xw & 15) << 4;
#pragma unroll
                for (int g = 0; g < 4; ++g) {
                    const int hbase = hb + tt * 32 + g * 8 + khalf * 4;
                    f16x4 pk;
#pragma unroll
                    for (int q = 0; q < 4; ++q) {
                        const float v = acc[tt][tx][g * 4 + q] + bb[hbase + q];
                        pk[q] = (_Float16)(1.0f - 2.0f * __builtin_amdgcn_rcpf(
                            __builtin_amdgcn_exp2f(v * 2.8853900817779268f) + 1.0f));
                    }
                    *reinterpret_cast<f16x4*>((char*)sH + xw * 256 + ((hbase * 2) ^ swz)) = pk;
                }
            }
    };

    for (int l = 0; l < 3; ++l) {
        __syncthreads();
        const float* __restrict__ wsrc = th + 2176 + l * 16512;
#pragma unroll
        for (int j = 0; j < 16; ++j) {
            const int flat = j * 1024 + tid * 4;
            const int hrow = flat >> 7;
            const int o    = flat & 127;
            const float a0 = wsrc[flat], a1 = wsrc[flat + 1], a2 = wsrc[flat + 2], a3 = wsrc[flat + 3];
            _Float16 h0 = (_Float16)a0, h1 = (_Float16)a1, h2 = (_Float16)a2, h3 = (_Float16)a3;
            f16x4 ph = {h0, h1, h2, h3};
            f16x4 pl = {(_Float16)(a0 - (float)h0), (_Float16)(a1 - (float)h1),
                        (_Float16)(a2 - (float)h2), (_Float16)(a3 - (float)h3)};
            const int boff = hrow * 256 + ((o * 2) ^ ((hrow & 15) << 4));
            *reinterpret_cast<f16x4*>((char*)sWhi + boff) = ph;
            *reinterpret_cast<f16x4*>((char*)sWlo + boff) = pl;
        }
        if (tid < 128) sB[(l + 1) & 1][tid] = wsrc[128 * 128 + tid];
        if (l == 2) {
            if (tid < 128) sWl[tid] = th[51712 + tid];
            if (tid == 128) sWl[128] = th[51840];
        }

        epilogue(sB[l & 1]);
        __syncthreads();

#pragma unroll
        for (int tt = 0; tt < 2; ++tt)
#pragma unroll
            for (int tx = 0; tx < 2; ++tx)
#pragma unroll
                for (int i = 0; i < 16; ++i) acc[tt][tx][i] = 0.0f;
#pragma unroll
        for (int kc = 0; kc < 8; ++kc) {
            const int kb = kc * 32 + khalf * 16;
            f16x8 ah[2], al[2], bv[2];
            ah[0] = *reinterpret_cast<const f16x8*>((const char*)sWhi + hA0 * 256 + (kb ^ swzA0));
            ah[1] = *reinterpret_cast<const f16x8*>((const char*)sWhi + hA1 * 256 + (kb ^ swzA1));
            al[0] = *reinterpret_cast<const f16x8*>((const char*)sWlo + hA0 * 256 + (kb ^ swzA0));
            al[1] = *reinterpret_cast<const f16x8*>((const char*)sWlo + hA1 * 256 + (kb ^ swzA1));
            bv[0] = *reinterpret_cast<const f16x8*>((const char*)sH   + xB0 * 256 + (kb ^ swzB0));
            bv[1] = *reinterpret_cast<const f16x8*>((const char*)sH   + xB1 * 256 + (kb ^ swzB1));
#pragma unroll
            for (int tt = 0; tt < 2; ++tt)
#pragma unroll
                for (int tx = 0; tx < 2; ++tx) {
                    acc[tt][tx] = MFMA(al[tt], bv[tx], acc[tt][tx]);
                    acc[tt][tx] = MFMA(ah[tt], bv[tx], acc[tt][tx]);
                }
        }
    }

    __syncthreads();
    epilogue(sB[1]);
    __syncthreads();

    if (tid < 128) {
        const int r   = tid;
        const int swz = (r & 15) << 4;
        float s = 0.0f;
#pragma unroll
        for (int c = 0; c < 16; ++c) {
            const int hc = (c + r) & 15;
            const f16x8 hv = *reinterpret_cast<const f16x8*>(
                (const char*)sH + r * 256 + ((hc * 16) ^ swz));
#pragma unroll
            for (int q = 0; q < 8; ++q) s += (float)hv[q] * sWl[hc * 8 + q];
        }
        out[(size_t)t * 4096 + (size_t)xt * 128 + r] = s + sWl[128];
    }
}

extern "C" void kernel_launch(void* const* d_in, const int* in_sizes, int n_in,
                              void* d_out, int out_size, void* d_ws, size_t ws_size,
                              hipStream_t stream)
{
    const float* x     = (const float*)d_in[0];
    const float* theta = (const float*)d_in[1];
    float* out = (float*)d_out;

    if (ws_size >= (size_t)WS_TOTAL) {
        prep_kernel<<<dim3(3280), dim3(256), 0, stream>>>(theta, x, (char*)d_ws);
        mlp_main<<<dim3(4096), dim3(THREADS), 0, stream>>>((const char*)d_ws, out);
    } else {
        mlp_kernel_fb<<<dim3(4096), dim3(THREADS), 0, stream>>>(x, theta, out);
    }
}

// Round 9
// 108.574 us; speedup vs baseline: 1.7243x; 1.0776x over previous
//
#include <hip/hip_runtime.h>

// Batched MLP, round 9: ONE barrier total. All three hidden W images persist
// in LDS (96 KB, 1 block/CU, 512 threads = 8 waves of 128h x 32x). After the
// single barrier, layers 1..3 run with no synchronization at all -- waves
// free-run and de-phase, so LDS/MFMA work of some waves overlaps the VALU
// (tanh) work of others instead of the measured chip-wide phase lockstep
// (serial-sum 14.7k cyc/layer vs overlapped-max ~7k).
// Numerics (validated, absmax 0.5625): prescaled W/b (2*log2e), f16 single
// weights hidden, hi/lo layer 0, tanh = 1 - 2*rcp(1+exp2(z)), RTZ pack.

#define IND      16
#define THREADS  512
#define PARAMS   51841
#define SCALE    2.8853900817779268f   // 2*log2(e)

#define WS_W0    12582912                  // [0,WS_W0): 128*3 hidden W images
#define WS_SC    (WS_W0 + 128 * 8192)      // per-t W0 frag images (hi|lo)
#define WS_X     (WS_SC + 128 * 4096)      // per-t scalar blocks
#define WS_XLO   (WS_X + 131072)           // x hi rows then lo rows
#define WS_TOTAL (WS_X + 262144)           // 14,417,920

// per-t scalar block (f32): +0 b0s(128) | +128 b1..3s(384) | +512 wl(128) | +640 bl

#define LDS_B    98304                      // 3 W images below
#define LDS_WL   (LDS_B + 1536)
#define LDS_SZ   (LDS_B + 2064)

typedef _Float16 f16x8 __attribute__((ext_vector_type(8)));
typedef _Float16 f16x4 __attribute__((ext_vector_type(4)));
typedef float    f32x16 __attribute__((ext_vector_type(16)));
typedef float    f32x4v __attribute__((ext_vector_type(4)));
typedef unsigned u32x2  __attribute__((ext_vector_type(2)));

union U4 { unsigned u[4]; f16x8 v; };

// z PRE-SCALED by 2*log2(e): tanh = 1 - 2*rcp(1 + exp2(z)).
// Saturates correctly (exp2 overflow -> inf -> rcp -> 0 -> 1; underflow -> -1).
__device__ __forceinline__ unsigned tanh2pk(float z0, float z1) {
    const float e0 = __builtin_amdgcn_exp2f(z0);
    const float e1 = __builtin_amdgcn_exp2f(z1);
    const float y0 = __builtin_fmaf(__builtin_amdgcn_rcpf(1.0f + e0), -2.0f, 1.0f);
    const float y1 = __builtin_fmaf(__builtin_amdgcn_rcpf(1.0f + e1), -2.0f, 1.0f);
    return __builtin_bit_cast(unsigned, __builtin_amdgcn_cvt_pkrtz(y0, y1));
}

#define MFMA(A, B, C) __builtin_amdgcn_mfma_f32_32x32x16_f16((A), (B), (C), 0, 0, 0)

__device__ __forceinline__ void gload16(const void* g, void* l) {
    __builtin_amdgcn_global_load_lds(
        (const __attribute__((address_space(1))) void*)g,
        (__attribute__((address_space(3))) void*)l, 16, 0, 0);
}

__device__ __forceinline__ void conv8(const float* __restrict__ s, char* hidst,
                                      char* lodst, float scale) {
    float v[8];
    *reinterpret_cast<float4*>(v)     = *reinterpret_cast<const float4*>(s);
    *reinterpret_cast<float4*>(v + 4) = *reinterpret_cast<const float4*>(s + 4);
    f16x8 hi, lo;
#pragma unroll
    for (int i = 0; i < 8; ++i) {
        const float sv = v[i] * scale;
        hi[i] = (_Float16)sv;
        lo[i] = (_Float16)(sv - (float)hi[i]);
    }
    *reinterpret_cast<f16x8*>(hidst) = hi;
    *reinterpret_cast<f16x8*>(lodst) = lo;
}

// ---------------------------------------------------------------------------
// prep:
//  [0,3072):     hidden W frag chunks (SCALED):
//                  (t*3+li)<<15 + ((h>>5)*8+kc)*1024 + (kh*32+(h&31))*16
//  [3072,3136):  W0 frag rows (SCALED): WS_W0 + t*8192 + h*32 (lo at +4096)
//  [3136,3264):  per-t scalar block (SCALED biases; wl/bl unscaled)
//  [3264,3280):  x rows (UNscaled): WS_X + row*32 (lo at WS_XLO + row*32)
// ---------------------------------------------------------------------------
__global__ __launch_bounds__(256)
void prep_kernel(const float* __restrict__ theta, const float* __restrict__ xin,
                 char* __restrict__ ws)
{
    const int b = blockIdx.x, tid = threadIdx.x;
    if (b < 3072) {
        const int t = b / 24, rem = b % 24, li = rem >> 3, hblk = rem & 7;
        const int h  = hblk * 16 + (tid >> 4);
        const int kc = (tid >> 1) & 7, kh = tid & 1;
        const float* src = theta + (size_t)t * PARAMS + 2176 + li * 16512
                         + h * 128 + kc * 16 + kh * 8;
        float v[8];
        *reinterpret_cast<float4*>(v)     = *reinterpret_cast<const float4*>(src);
        *reinterpret_cast<float4*>(v + 4) = *reinterpret_cast<const float4*>(src + 4);
        f16x8 p;
#pragma unroll
        for (int i = 0; i < 8; ++i) p[i] = (_Float16)(v[i] * SCALE);
        char* img = ws + ((size_t)(t * 3 + li) << 15);
        *reinterpret_cast<f16x8*>(img + ((h >> 5) * 8 + kc) * 1024
                                      + (kh * 32 + (h & 31)) * 16) = p;
    } else if (b < 3136) {
        const int gid = (b - 3072) * 256 + tid;
        const int t = gid >> 7, h = gid & 127;
        const float* src = theta + (size_t)t * PARAMS + h * IND;
        char* dst = ws + WS_W0 + (size_t)t * 8192 + h * 32;
        conv8(src,     dst,      dst + 4096,      SCALE);
        conv8(src + 8, dst + 16, dst + 4096 + 16, SCALE);
    } else if (b < 3264) {
        const int t = b - 3136;
        const float* th = theta + (size_t)t * PARAMS;
        float* base = reinterpret_cast<float*>(ws + WS_SC + (size_t)t * 4096);
        if (tid < 128) base[tid] = SCALE * th[2048 + tid];                 // b0s
        for (int k = tid; k < 384; k += 256)                               // b1..3s
            base[128 + k] = SCALE * th[2176 + (k >> 7) * 16512 + 16384 + (k & 127)];
        if (tid < 128) base[512 + tid] = th[51712 + tid];                  // wl
        if (tid == 0)  base[640] = th[51840];                              // bl
    } else {
        const int row = (b - 3264) * 256 + tid;
        const float* src = xin + (size_t)row * IND;
        char* hid = ws + WS_X   + (size_t)row * 32;
        char* lod = ws + WS_XLO + (size_t)row * 32;
        conv8(src,     hid,      lod,      1.0f);
        conv8(src + 8, hid + 16, lod + 16, 1.0f);
    }
}

// ---------------------------------------------------------------------------
// main: 512 threads, 1 block/CU (LDS 100KB), ONE barrier.
// ---------------------------------------------------------------------------
__global__ __launch_bounds__(THREADS, 1)
void mlp_main(const char* __restrict__ ws, float* __restrict__ out)
{
    __shared__ __align__(16) char sL[LDS_SZ];

    const int tid = threadIdx.x, bid = blockIdx.x;
    const int sw  = (bid & 7) * 256 + (bid >> 3);   // XCD-bijective (2048%8==0)
    const int t   = sw >> 4, xt = sw & 15;
    const int lane = tid & 63, w = tid >> 6, r31 = lane & 31, khalf = lane >> 5;
    const int bpa  = (lane ^ 32) << 2;
    (void)bpa;

    const float* __restrict__ wsc = reinterpret_cast<const float*>(
        ws + WS_SC + (size_t)t * 4096);

    // ---- issue stage of W1|W2|W3 (96KB contiguous) -> LDS[0,96K) ----
    {
        const char* img = ws + ((size_t)(t * 3) << 15);
#pragma unroll
        for (int c = 0; c < 12; ++c) {
            const int o = (c * 512 + tid) * 16;
            gload16(img + o, sL + o);
        }
    }
    // ---- stage scaled b1..3 + wl + bl tables ----
    for (int k = tid; k < 513; k += THREADS)
        *reinterpret_cast<float*>(sL + LDS_B + k * 4) = wsc[128 + k];

    // ---- layer 0 (global operands; overlaps the staging DMAs) ----
    f32x16 acc[4];
    {
        const char* w0i = ws + WS_W0 + (size_t)t * 8192;
        const int ro = r31 * 32 + khalf * 16;
        const int xrow = (xt * 256 + w * 32) * 32;   // byte offset of wave's x rows
        const f16x8 B0h = *reinterpret_cast<const f16x8*>(ws + WS_X   + xrow + ro);
        const f16x8 B0l = *reinterpret_cast<const f16x8*>(ws + WS_XLO + xrow + ro);
#pragma unroll
        for (int tt = 0; tt < 4; ++tt) {
#pragma unroll
            for (int g = 0; g < 4; ++g) {
                const f32x4v bv = *reinterpret_cast<const f32x4v*>(
                    wsc + tt * 32 + g * 8 + khalf * 4);
                acc[tt][4 * g + 0] = bv[0]; acc[tt][4 * g + 1] = bv[1];
                acc[tt][4 * g + 2] = bv[2]; acc[tt][4 * g + 3] = bv[3];
            }
            const f16x8 Ah = *reinterpret_cast<const f16x8*>(w0i + tt * 1024 + ro);
            const f16x8 Al = *reinterpret_cast<const f16x8*>(w0i + 4096 + tt * 1024 + ro);
            acc[tt] = MFMA(Al, B0h, acc[tt]);
            acc[tt] = MFMA(Ah, B0l, acc[tt]);
            acc[tt] = MFMA(Ah, B0h, acc[tt]);
        }
    }

    f16x8 Bf[8];
    // tanh(acc) -> f16 (RTZ) -> permlane32_swap assembles next-layer B-frags.
    auto activate_pack = [&]() {
#pragma unroll
        for (int tt = 0; tt < 4; ++tt) {
            unsigned P0[4], P1[4];
#pragma unroll
            for (int g = 0; g < 4; ++g) {
                P0[g] = tanh2pk(acc[tt][4 * g + 0], acc[tt][4 * g + 1]);
                P1[g] = tanh2pk(acc[tt][4 * g + 2], acc[tt][4 * g + 3]);
            }
#pragma unroll
            for (int j = 0; j < 2; ++j) {        // kc = 2*tt + j
#if __has_builtin(__builtin_amdgcn_permlane32_swap)
                const u32x2 r0 = __builtin_amdgcn_permlane32_swap(
                    P0[2 * j], P0[2 * j + 1], false, false);
                const u32x2 r1 = __builtin_amdgcn_permlane32_swap(
                    P1[2 * j], P1[2 * j + 1], false, false);
                U4 u;
                u.u[0] = r0[0]; u.u[1] = r1[0]; u.u[2] = r0[1]; u.u[3] = r1[1];
#else
                const unsigned s0 = khalf ? P0[2 * j] : P0[2 * j + 1];
                const unsigned s1 = khalf ? P1[2 * j] : P1[2 * j + 1];
                const unsigned q0 = (unsigned)__builtin_amdgcn_ds_bpermute(bpa, (int)s0);
                const unsigned q1 = (unsigned)__builtin_amdgcn_ds_bpermute(bpa, (int)s1);
                U4 u;
                u.u[0] = khalf ? q0 : P0[2 * j];
                u.u[1] = khalf ? q1 : P1[2 * j];
                u.u[2] = khalf ? P0[2 * j + 1] : q0;
                u.u[3] = khalf ? P1[2 * j + 1] : q1;
#endif
                Bf[2 * tt + j] = u.v;
            }
        }
    };
    activate_pack();

    __syncthreads();   // THE ONLY BARRIER: drains vmcnt -> W1..W3 + tables visible

    // ---- hidden layers 1..3: barrier-free, waves de-phase ----
#pragma unroll
    for (int l = 0; l < 3; ++l) {
        const char* wimg  = sL + l * 32768;
        const char* btab  = sL + LDS_B + l * 512;
        __builtin_amdgcn_s_setprio(1);
#pragma unroll
        for (int tt = 0; tt < 4; ++tt) {
#pragma unroll
            for (int g = 0; g < 4; ++g) {
                const f32x4v bv = *reinterpret_cast<const f32x4v*>(
                    btab + (tt * 32 + g * 8) * 4 + khalf * 16);
                acc[tt][4 * g + 0] = bv[0]; acc[tt][4 * g + 1] = bv[1];
                acc[tt][4 * g + 2] = bv[2]; acc[tt][4 * g + 3] = bv[3];
            }
#pragma unroll
            for (int kc = 0; kc < 8; ++kc) {
                const f16x8 a = *reinterpret_cast<const f16x8*>(
                    wimg + (tt * 8 + kc) * 1024 + lane * 16);
                acc[tt] = MFMA(a, Bf[kc], acc[tt]);
            }
        }
        __builtin_amdgcn_s_setprio(0);
        if (l < 2) activate_pack();
    }
    activate_pack();   // h4 -> Bf (keeps acc for final tanh below)

    // ---- final: out[x] = wl . tanh(acc) + bl  (f32, rcp tanh) ----
    float s = 0.0f;
#pragma unroll
    for (int tt = 0; tt < 4; ++tt)
#pragma unroll
        for (int g = 0; g < 4; ++g) {
            const f32x4v wv = *reinterpret_cast<const f32x4v*>(
                sL + LDS_WL + (tt * 32 + g * 8) * 4 + khalf * 16);
#pragma unroll
            for (int q = 0; q < 4; ++q) {
                const float z = acc[tt][4 * g + q];
                const float e = __builtin_amdgcn_exp2f(z);
                const float y = __builtin_fmaf(
                    __builtin_amdgcn_rcpf(1.0f + e), -2.0f, 1.0f);
                s = __builtin_fmaf(y, wv[q], s);
            }
        }
    const float sp = __builtin_bit_cast(float,
        __builtin_amdgcn_ds_bpermute(bpa, __builtin_bit_cast(int, s)));
    const float res = s + sp + *reinterpret_cast<const float*>(sL + LDS_WL + 512);
    if (!khalf) out[(size_t)t * 4096 + xt * 256 + w * 32 + r31] = res;
}

// ---------------------------------------------------------------------------
// Fallback (self-contained, known-good round-1 kernel) if ws is too small.
// ---------------------------------------------------------------------------
__global__ __launch_bounds__(256, 1)
void mlp_kernel_fb(const float* __restrict__ xin,
                   const float* __restrict__ theta,
                   float* __restrict__ out)
{
    __shared__ __align__(16) _Float16 sH   [128 * 128];
    __shared__ __align__(16) _Float16 sWhi [128 * 128];
    __shared__ __align__(16) _Float16 sWlo [128 * 128];
    __shared__ __align__(16) _Float16 sX0hi[128 * IND];
    __shared__ __align__(16) _Float16 sX0lo[128 * IND];
    __shared__ __align__(16) _Float16 sW0hi[128 * IND];
    __shared__ __align__(16) _Float16 sW0lo[128 * IND];
    __shared__ float sB[2][128];
    __shared__ float sWl[129];

    const int tid = threadIdx.x;
    const int bid = blockIdx.x;
    const int sw  = (bid & 7) * 512 + (bid >> 3);
    const int t   = sw >> 5;
    const int xt  = sw & 31;
    const float* __restrict__ th = theta + (size_t)t * PARAMS;
    const float* __restrict__ xg = xin   + (size_t)xt * (128 * IND);

#pragma unroll
    for (int j = 0; j < 2; ++j) {
        const int flat = j * 1024 + tid * 4;
        const float4 v = *reinterpret_cast<const float4*>(xg + flat);
        _Float16 h0 = (_Float16)v.x, h1 = (_Float16)v.y, h2 = (_Float16)v.z, h3 = (_Float16)v.w;
        f16x4 ph = {h0, h1, h2, h3};
        f16x4 pl = {(_Float16)(v.x - (float)h0), (_Float16)(v.y - (float)h1),
                    (_Float16)(v.z - (float)h2), (_Float16)(v.w - (float)h3)};
        *reinterpret_cast<f16x4*>(&sX0hi[flat]) = ph;
        *reinterpret_cast<f16x4*>(&sX0lo[flat]) = pl;
    }
#pragma unroll
    for (int j = 0; j < 2; ++j) {
        const int flat = j * 1024 + tid * 4;
        const float a0 = th[flat], a1 = th[flat + 1], a2 = th[flat + 2], a3 = th[flat + 3];
        _Float16 h0 = (_Float16)a0, h1 = (_Float16)a1, h2 = (_Float16)a2, h3 = (_Float16)a3;
        f16x4 ph = {h0, h1, h2, h3};
        f16x4 pl = {(_Float16)(a0 - (float)h0), (_Float16)(a1 - (float)h1),
                    (_Float16)(a2 - (float)h2), (_Float16)(a3 - (float)h3)};
        *reinterpret_cast<f16x4*>(&sW0hi[flat]) = ph;
        *reinterpret_cast<f16x4*>(&sW0lo[flat]) = pl;
    }
    if (tid < 128) sB[0][tid] = th[IND * 128 + tid];
    __syncthreads();

    const int lane  = tid & 63;
    const int w     = tid >> 6;
    const int r31   = lane & 31;
    const int khalf = lane >> 5;
    const int hb    = (w >> 1) * 64;
    const int xb    = (w & 1) * 64;
    const int hA0 = hb + r31,  hA1 = hb + 32 + r31;
    const int xB0 = xb + r31,  xB1 = xb + 32 + r31;
    const int swzA0 = (hA0 & 15) << 4, swzA1 = (hA1 & 15) << 4;
    const int swzB0 = (xB0 & 15) << 4, swzB1 = (xB1 & 15) << 4;

    f32x16 acc[2][2];

    {
        const int kb = khalf * 16;
        f16x8 ah[2], al[2], bh[2], bl[2];
        ah[0] = *reinterpret_cast<const f16x8*>((const char*)sW0hi + hA0 * 32 + kb);
        ah[1] = *reinterpret_cast<const f16x8*>((const char*)sW0hi + hA1 * 32 + kb);
        al[0] = *reinterpret_cast<const f16x8*>((const char*)sW0lo + hA0 * 32 + kb);
        al[1] = *reinterpret_cast<const f16x8*>((const char*)sW0lo + hA1 * 32 + kb);
        bh[0] = *reinterpret_cast<const f16x8*>((const char*)sX0hi + xB0 * 32 + kb);
        bh[1] = *reinterpret_cast<const f16x8*>((const char*)sX0hi + xB1 * 32 + kb);
        bl[0] = *reinterpret_cast<const f16x8*>((const char*)sX0lo + xB0 * 32 + kb);
        bl[1] = *reinterpret_cast<const f16x8*>((const char*)sX0lo + xB1 * 32 + kb);
#pragma unroll
        for (int tt = 0; tt < 2; ++tt)
#pragma unroll
            for (int tx = 0; tx < 2; ++tx) {
                f32x16 a;
#pragma unroll
                for (int i = 0; i < 16; ++i) a[i] = 0.0f;
                a = MFMA(al[tt], bh[tx], a);
                a = MFMA(ah[tt], bl[tx], a);
                a = MFMA(ah[tt], bh[tx], a);
                acc[tt][tx] = a;
            }
    }

    auto epilogue = [&](const float* __restrict__ bb) {
#pragma unroll
        for (int tt = 0; tt < 2; ++tt)
#pragma unroll
            for (int tx = 0; tx < 2; ++tx) {
                const int xw  = xb + tx * 32 + r31;
                const int swz = (xw & 15) << 4;
#pragma unroll
                for (int g = 0; g < 4; ++g) {
                    const int hbase = hb + tt * 32 + g * 8 + khalf * 4;
                    f16x4 pk;
#pragma unroll
                    for (int q = 0; q < 4; ++q) {
                        const float v = acc[tt][tx][g * 4 + q] + bb[hbase + q];
                        pk[q] = (_Float16)(1.0f - 2.0f * __builtin_amdgcn_rcpf(
                            __builtin_amdgcn_exp2f(v * 2.8853900817779268f) + 1.0f));
                    }
                    *reinterpret_cast<f16x4*>((char*)sH + xw * 256 + ((hbase * 2) ^ swz)) = pk;
                }
            }
    };

    for (int l = 0; l < 3; ++l) {
        __syncthreads();
        const float* __restrict__ wsrc = th + 2176 + l * 16512;
#pragma unroll
        for (int j = 0; j < 16; ++j) {
            const int flat = j * 1024 + tid * 4;
            const int hrow = flat >> 7;
            const int o    = flat & 127;
            const float a0 = wsrc[flat], a1 = wsrc[flat + 1], a2 = wsrc[flat + 2], a3 = wsrc[flat + 3];
            _Float16 h0 = (_Float16)a0, h1 = (_Float16)a1, h2 = (_Float16)a2, h3 = (_Float16)a3;
            f16x4 ph = {h0, h1, h2, h3};
            f16x4 pl = {(_Float16)(a0 - (float)h0), (_Float16)(a1 - (float)h1),
                        (_Float16)(a2 - (float)h2), (_Float16)(a3 - (float)h3)};
            const int boff = hrow * 256 + ((o * 2) ^ ((hrow & 15) << 4));
            *reinterpret_cast<f16x4*>((char*)sWhi + boff) = ph;
            *reinterpret_cast<f16x4*>((char*)sWlo + boff) = pl;
        }
        if (tid < 128) sB[(l + 1) & 1][tid] = wsrc[128 * 128 + tid];
        if (l == 2) {
            if (tid < 128) sWl[tid] = th[51712 + tid];
            if (tid == 128) sWl[128] = th[51840];
        }

        epilogue(sB[l & 1]);
        __syncthreads();

#pragma unroll
        for (int tt = 0; tt < 2; ++tt)
#pragma unroll
            for (int tx = 0; tx < 2; ++tx)
#pragma unroll
                for (int i = 0; i < 16; ++i) acc[tt][tx][i] = 0.0f;
#pragma unroll
        for (int kc = 0; kc < 8; ++kc) {
            const int kb = kc * 32 + khalf * 16;
            f16x8 ah[2], al[2], bv[2];
            ah[0] = *reinterpret_cast<const f16x8*>((const char*)sWhi + hA0 * 256 + (kb ^ swzA0));
            ah[1] = *reinterpret_cast<const f16x8*>((const char*)sWhi + hA1 * 256 + (kb ^ swzA1));
            al[0] = *reinterpret_cast<const f16x8*>((const char*)sWlo + hA0 * 256 + (kb ^ swzA0));
            al[1] = *reinterpret_cast<const f16x8*>((const char*)sWlo + hA1 * 256 + (kb ^ swzA1));
            bv[0] = *reinterpret_cast<const f16x8*>((const char*)sH   + xB0 * 256 + (kb ^ swzB0));
            bv[1] = *reinterpret_cast<const f16x8*>((const char*)sH   + xB1 * 256 + (kb ^ swzB1));
#pragma unroll
            for (int tt = 0; tt < 2; ++tt)
#pragma unroll
                for (int tx = 0; tx < 2; ++tx) {
                    acc[tt][tx] = MFMA(al[tt], bv[tx], acc[tt][tx]);
                    acc[tt][tx] = MFMA(ah[tt], bv[tx], acc[tt][tx]);
                }
        }
    }

    __syncthreads();
    epilogue(sB[1]);
    __syncthreads();

    if (tid < 128) {
        const int r   = tid;
        const int swz = (r & 15) << 4;
        float s = 0.0f;
#pragma unroll
        for (int c = 0; c < 16; ++c) {
            const int hc = (c + r) & 15;
            const f16x8 hv = *reinterpret_cast<const f16x8*>(
                (const char*)sH + r * 256 + ((hc * 16) ^ swz));
#pragma unroll
            for (int q = 0; q < 8; ++q) s += (float)hv[q] * sWl[hc * 8 + q];
        }
        out[(size_t)t * 4096 + (size_t)xt * 128 + r] = s + sWl[128];
    }
}

extern "C" void kernel_launch(void* const* d_in, const int* in_sizes, int n_in,
                              void* d_out, int out_size, void* d_ws, size_t ws_size,
                              hipStream_t stream)
{
    const float* x     = (const float*)d_in[0];
    const float* theta = (const float*)d_in[1];
    float* out = (float*)d_out;

    if (ws_size >= (size_t)WS_TOTAL) {
        prep_kernel<<<dim3(3280), dim3(256), 0, stream>>>(theta, x, (char*)d_ws);
        mlp_main<<<dim3(2048), dim3(THREADS), 0, stream>>>((const char*)d_ws, out);
    } else {
        mlp_kernel_fb<<<dim3(4096), dim3(256), 0, stream>>>(x, theta, out);
    }
}

// Round 10
// 100.351 us; speedup vs baseline: 1.8656x; 1.0819x over previous
//
#include <hip/hip_runtime.h>

// Batched MLP, round 10: round-9 barrier-free persistent-W structure with
// DOUBLE the TLP: 1024-thread blocks (16 free-running waves = 4 waves/SIMD),
// ONE barrier total, grid 1024 (4 generations). launch_bounds(1024,4) caps
// unified regs at 128/wave (64 arch + 64 AGPR measured for these loops).
// Numerics unchanged (absmax 0.578 validated): prescaled W/b (2*log2e),
// hi/lo layer 0, f16 hidden weights, tanh = 1 - 2*rcp(1+exp2(z)), RTZ pack.

#define IND      16
#define THREADS  1024
#define PARAMS   51841
#define SCALE    2.8853900817779268f   // 2*log2(e)

#define WS_W0    12582912                  // [0,WS_W0): 128*3 hidden W images
#define WS_SC    (WS_W0 + 128 * 8192)      // per-t W0 frag images (hi|lo)
#define WS_X     (WS_SC + 128 * 4096)      // per-t scalar blocks
#define WS_XLO   (WS_X + 131072)           // x hi rows then lo rows
#define WS_TOTAL (WS_X + 262144)           // 14,417,920

// per-t scalar block (f32): +0 b0s(128) | +128 b1..3s(384) | +512 wl(128) | +640 bl

#define LDS_B    98304                      // 3 W images below
#define LDS_WL   (LDS_B + 1536)
#define LDS_SZ   (LDS_B + 2064)

typedef _Float16 f16x8 __attribute__((ext_vector_type(8)));
typedef _Float16 f16x4 __attribute__((ext_vector_type(4)));
typedef float    f32x16 __attribute__((ext_vector_type(16)));
typedef float    f32x4v __attribute__((ext_vector_type(4)));
typedef unsigned u32x2  __attribute__((ext_vector_type(2)));

union U4 { unsigned u[4]; f16x8 v; };

// z PRE-SCALED by 2*log2(e): tanh = 1 - 2*rcp(1 + exp2(z)).
// Saturates correctly (exp2 overflow -> inf -> rcp -> 0 -> 1; underflow -> -1).
__device__ __forceinline__ unsigned tanh2pk(float z0, float z1) {
    const float e0 = __builtin_amdgcn_exp2f(z0);
    const float e1 = __builtin_amdgcn_exp2f(z1);
    const float y0 = __builtin_fmaf(__builtin_amdgcn_rcpf(1.0f + e0), -2.0f, 1.0f);
    const float y1 = __builtin_fmaf(__builtin_amdgcn_rcpf(1.0f + e1), -2.0f, 1.0f);
    return __builtin_bit_cast(unsigned, __builtin_amdgcn_cvt_pkrtz(y0, y1));
}

#define MFMA(A, B, C) __builtin_amdgcn_mfma_f32_32x32x16_f16((A), (B), (C), 0, 0, 0)

__device__ __forceinline__ void gload16(const void* g, void* l) {
    __builtin_amdgcn_global_load_lds(
        (const __attribute__((address_space(1))) void*)g,
        (__attribute__((address_space(3))) void*)l, 16, 0, 0);
}

__device__ __forceinline__ void conv8(const float* __restrict__ s, char* hidst,
                                      char* lodst, float scale) {
    float v[8];
    *reinterpret_cast<float4*>(v)     = *reinterpret_cast<const float4*>(s);
    *reinterpret_cast<float4*>(v + 4) = *reinterpret_cast<const float4*>(s + 4);
    f16x8 hi, lo;
#pragma unroll
    for (int i = 0; i < 8; ++i) {
        const float sv = v[i] * scale;
        hi[i] = (_Float16)sv;
        lo[i] = (_Float16)(sv - (float)hi[i]);
    }
    *reinterpret_cast<f16x8*>(hidst) = hi;
    *reinterpret_cast<f16x8*>(lodst) = lo;
}

// ---------------------------------------------------------------------------
// prep (identical layout to round 9):
//  [0,3072):     hidden W frag chunks (SCALED):
//                  (t*3+li)<<15 + ((h>>5)*8+kc)*1024 + (kh*32+(h&31))*16
//  [3072,3136):  W0 frag rows (SCALED): WS_W0 + t*8192 + h*32 (lo at +4096)
//  [3136,3264):  per-t scalar block (SCALED biases; wl/bl unscaled)
//  [3264,3280):  x rows (UNscaled): WS_X + row*32 (lo at WS_XLO + row*32)
// ---------------------------------------------------------------------------
__global__ __launch_bounds__(256)
void prep_kernel(const float* __restrict__ theta, const float* __restrict__ xin,
                 char* __restrict__ ws)
{
    const int b = blockIdx.x, tid = threadIdx.x;
    if (b < 3072) {
        const int t = b / 24, rem = b % 24, li = rem >> 3, hblk = rem & 7;
        const int h  = hblk * 16 + (tid >> 4);
        const int kc = (tid >> 1) & 7, kh = tid & 1;
        const float* src = theta + (size_t)t * PARAMS + 2176 + li * 16512
                         + h * 128 + kc * 16 + kh * 8;
        float v[8];
        *reinterpret_cast<float4*>(v)     = *reinterpret_cast<const float4*>(src);
        *reinterpret_cast<float4*>(v + 4) = *reinterpret_cast<const float4*>(src + 4);
        f16x8 p;
#pragma unroll
        for (int i = 0; i < 8; ++i) p[i] = (_Float16)(v[i] * SCALE);
        char* img = ws + ((size_t)(t * 3 + li) << 15);
        *reinterpret_cast<f16x8*>(img + ((h >> 5) * 8 + kc) * 1024
                                      + (kh * 32 + (h & 31)) * 16) = p;
    } else if (b < 3136) {
        const int gid = (b - 3072) * 256 + tid;
        const int t = gid >> 7, h = gid & 127;
        const float* src = theta + (size_t)t * PARAMS + h * IND;
        char* dst = ws + WS_W0 + (size_t)t * 8192 + h * 32;
        conv8(src,     dst,      dst + 4096,      SCALE);
        conv8(src + 8, dst + 16, dst + 4096 + 16, SCALE);
    } else if (b < 3264) {
        const int t = b - 3136;
        const float* th = theta + (size_t)t * PARAMS;
        float* base = reinterpret_cast<float*>(ws + WS_SC + (size_t)t * 4096);
        if (tid < 128) base[tid] = SCALE * th[2048 + tid];                 // b0s
        for (int k = tid; k < 384; k += 256)                               // b1..3s
            base[128 + k] = SCALE * th[2176 + (k >> 7) * 16512 + 16384 + (k & 127)];
        if (tid < 128) base[512 + tid] = th[51712 + tid];                  // wl
        if (tid == 0)  base[640] = th[51840];                              // bl
    } else {
        const int row = (b - 3264) * 256 + tid;
        const float* src = xin + (size_t)row * IND;
        char* hid = ws + WS_X   + (size_t)row * 32;
        char* lod = ws + WS_XLO + (size_t)row * 32;
        conv8(src,     hid,      lod,      1.0f);
        conv8(src + 8, hid + 16, lod + 16, 1.0f);
    }
}

// ---------------------------------------------------------------------------
// main: 1024 threads (16 waves, 4/SIMD), 1 block/CU (LDS 100KB), ONE barrier.
// ---------------------------------------------------------------------------
__global__ __launch_bounds__(THREADS, 4)
void mlp_main(const char* __restrict__ ws, float* __restrict__ out)
{
    __shared__ __align__(16) char sL[LDS_SZ];

    const int tid = threadIdx.x, bid = blockIdx.x;
    const int sw  = (bid & 7) * 128 + (bid >> 3);   // XCD-bijective (1024%8==0)
    const int t   = sw >> 3, xt = sw & 7;           // xt: 512-x tile index
    const int lane = tid & 63, w = tid >> 6, r31 = lane & 31, khalf = lane >> 5;
    const int bpa  = (lane ^ 32) << 2;
    (void)bpa;

    const float* __restrict__ wsc = reinterpret_cast<const float*>(
        ws + WS_SC + (size_t)t * 4096);

    // ---- issue stage of W1|W2|W3 (96KB contiguous) -> LDS[0,96K) ----
    {
        const char* img = ws + ((size_t)(t * 3) << 15);
#pragma unroll
        for (int c = 0; c < 6; ++c) {
            const int o = (c * 1024 + tid) * 16;
            gload16(img + o, sL + o);
        }
    }
    // ---- stage scaled b1..3 + wl + bl tables ----
    if (tid < 513)
        *reinterpret_cast<float*>(sL + LDS_B + tid * 4) = wsc[128 + tid];

    // ---- layer 0 (global operands; overlaps the staging DMAs) ----
    f32x16 acc[4];
    {
        const char* w0i = ws + WS_W0 + (size_t)t * 8192;
        const int ro = r31 * 32 + khalf * 16;
        const int xrow = (xt * 512 + w * 32) * 32;   // byte offset of wave's x rows
        const f16x8 B0h = *reinterpret_cast<const f16x8*>(ws + WS_X   + xrow + ro);
        const f16x8 B0l = *reinterpret_cast<const f16x8*>(ws + WS_XLO + xrow + ro);
#pragma unroll
        for (int tt = 0; tt < 4; ++tt) {
#pragma unroll
            for (int g = 0; g < 4; ++g) {
                const f32x4v bv = *reinterpret_cast<const f32x4v*>(
                    wsc + tt * 32 + g * 8 + khalf * 4);
                acc[tt][4 * g + 0] = bv[0]; acc[tt][4 * g + 1] = bv[1];
                acc[tt][4 * g + 2] = bv[2]; acc[tt][4 * g + 3] = bv[3];
            }
            const f16x8 Ah = *reinterpret_cast<const f16x8*>(w0i + tt * 1024 + ro);
            const f16x8 Al = *reinterpret_cast<const f16x8*>(w0i + 4096 + tt * 1024 + ro);
            acc[tt] = MFMA(Al, B0h, acc[tt]);
            acc[tt] = MFMA(Ah, B0l, acc[tt]);
            acc[tt] = MFMA(Ah, B0h, acc[tt]);
        }
    }

    f16x8 Bf[8];
    // tanh(acc) -> f16 (RTZ) -> permlane32_swap assembles next-layer B-frags.
    auto activate_pack = [&]() {
#pragma unroll
        for (int tt = 0; tt < 4; ++tt) {
            unsigned P0[4], P1[4];
#pragma unroll
            for (int g = 0; g < 4; ++g) {
                P0[g] = tanh2pk(acc[tt][4 * g + 0], acc[tt][4 * g + 1]);
                P1[g] = tanh2pk(acc[tt][4 * g + 2], acc[tt][4 * g + 3]);
            }
#pragma unroll
            for (int j = 0; j < 2; ++j) {        // kc = 2*tt + j
#if __has_builtin(__builtin_amdgcn_permlane32_swap)
                const u32x2 r0 = __builtin_amdgcn_permlane32_swap(
                    P0[2 * j], P0[2 * j + 1], false, false);
                const u32x2 r1 = __builtin_amdgcn_permlane32_swap(
                    P1[2 * j], P1[2 * j + 1], false, false);
                U4 u;
                u.u[0] = r0[0]; u.u[1] = r1[0]; u.u[2] = r0[1]; u.u[3] = r1[1];
#else
                const unsigned s0 = khalf ? P0[2 * j] : P0[2 * j + 1];
                const unsigned s1 = khalf ? P1[2 * j] : P1[2 * j + 1];
                const unsigned q0 = (unsigned)__builtin_amdgcn_ds_bpermute(bpa, (int)s0);
                const unsigned q1 = (unsigned)__builtin_amdgcn_ds_bpermute(bpa, (int)s1);
                U4 u;
                u.u[0] = khalf ? q0 : P0[2 * j];
                u.u[1] = khalf ? q1 : P1[2 * j];
                u.u[2] = khalf ? P0[2 * j + 1] : q0;
                u.u[3] = khalf ? P1[2 * j + 1] : q1;
#endif
                Bf[2 * tt + j] = u.v;
            }
        }
    };
    activate_pack();

    __syncthreads();   // THE ONLY BARRIER: drains vmcnt -> W1..W3 + tables visible

    // ---- hidden layers 1..3: barrier-free, 16 waves de-phase ----
#pragma unroll
    for (int l = 0; l < 3; ++l) {
        const char* wimg  = sL + l * 32768;
        const char* btab  = sL + LDS_B + l * 512;
        __builtin_amdgcn_s_setprio(1);
#pragma unroll
        for (int tt = 0; tt < 4; ++tt) {
#pragma unroll
            for (int g = 0; g < 4; ++g) {
                const f32x4v bv = *reinterpret_cast<const f32x4v*>(
                    btab + (tt * 32 + g * 8) * 4 + khalf * 16);
                acc[tt][4 * g + 0] = bv[0]; acc[tt][4 * g + 1] = bv[1];
                acc[tt][4 * g + 2] = bv[2]; acc[tt][4 * g + 3] = bv[3];
            }
#pragma unroll
            for (int kc = 0; kc < 8; ++kc) {
                const f16x8 a = *reinterpret_cast<const f16x8*>(
                    wimg + (tt * 8 + kc) * 1024 + lane * 16);
                acc[tt] = MFMA(a, Bf[kc], acc[tt]);
            }
        }
        __builtin_amdgcn_s_setprio(0);
        if (l < 2) activate_pack();
    }

    // ---- final: out[x] = wl . tanh(acc) + bl  (f32, rcp tanh) ----
    float s = 0.0f;
#pragma unroll
    for (int tt = 0; tt < 4; ++tt)
#pragma unroll
        for (int g = 0; g < 4; ++g) {
            const f32x4v wv = *reinterpret_cast<const f32x4v*>(
                sL + LDS_WL + (tt * 32 + g * 8) * 4 + khalf * 16);
#pragma unroll
            for (int q = 0; q < 4; ++q) {
                const float z = acc[tt][4 * g + q];
                const float e = __builtin_amdgcn_exp2f(z);
                const float y = __builtin_fmaf(
                    __builtin_amdgcn_rcpf(1.0f + e), -2.0f, 1.0f);
                s = __builtin_fmaf(y, wv[q], s);
            }
        }
    const float sp = __builtin_bit_cast(float,
        __builtin_amdgcn_ds_bpermute(bpa, __builtin_bit_cast(int, s)));
    const float res = s + sp + *reinterpret_cast<const float*>(sL + LDS_WL + 512);
    if (!khalf) out[(size_t)t * 4096 + xt * 512 + w * 32 + r31] = res;
}

// ---------------------------------------------------------------------------
// Fallback (self-contained, known-good round-1 kernel) if ws is too small.
// ---------------------------------------------------------------------------
__global__ __launch_bounds__(256, 1)
void mlp_kernel_fb(const float* __restrict__ xin,
                   const float* __restrict__ theta,
                   float* __restrict__ out)
{
    __shared__ __align__(16) _Float16 sH   [128 * 128];
    __shared__ __align__(16) _Float16 sWhi [128 * 128];
    __shared__ __align__(16) _Float16 sWlo [128 * 128];
    __shared__ __align__(16) _Float16 sX0hi[128 * IND];
    __shared__ __align__(16) _Float16 sX0lo[128 * IND];
    __shared__ __align__(16) _Float16 sW0hi[128 * IND];
    __shared__ __align__(16) _Float16 sW0lo[128 * IND];
    __shared__ float sB[2][128];
    __shared__ float sWl[129];

    const int tid = threadIdx.x;
    const int bid = blockIdx.x;
    const int sw  = (bid & 7) * 512 + (bid >> 3);
    const int t   = sw >> 5;
    const int xt  = sw & 31;
    const float* __restrict__ th = theta + (size_t)t * PARAMS;
    const float* __restrict__ xg = xin   + (size_t)xt * (128 * IND);

#pragma unroll
    for (int j = 0; j < 2; ++j) {
        const int flat = j * 1024 + tid * 4;
        const float4 v = *reinterpret_cast<const float4*>(xg + flat);
        _Float16 h0 = (_Float16)v.x, h1 = (_Float16)v.y, h2 = (_Float16)v.z, h3 = (_Float16)v.w;
        f16x4 ph = {h0, h1, h2, h3};
        f16x4 pl = {(_Float16)(v.x - (float)h0), (_Float16)(v.y - (float)h1),
                    (_Float16)(v.z - (float)h2), (_Float16)(v.w - (float)h3)};
        *reinterpret_cast<f16x4*>(&sX0hi[flat]) = ph;
        *reinterpret_cast<f16x4*>(&sX0lo[flat]) = pl;
    }
#pragma unroll
    for (int j = 0; j < 2; ++j) {
        const int flat = j * 1024 + tid * 4;
        const float a0 = th[flat], a1 = th[flat + 1], a2 = th[flat + 2], a3 = th[flat + 3];
        _Float16 h0 = (_Float16)a0, h1 = (_Float16)a1, h2 = (_Float16)a2, h3 = (_Float16)a3;
        f16x4 ph = {h0, h1, h2, h3};
        f16x4 pl = {(_Float16)(a0 - (float)h0), (_Float16)(a1 - (float)h1),
                    (_Float16)(a2 - (float)h2), (_Float16)(a3 - (float)h3)};
        *reinterpret_cast<f16x4*>(&sW0hi[flat]) = ph;
        *reinterpret_cast<f16x4*>(&sW0lo[flat]) = pl;
    }
    if (tid < 128) sB[0][tid] = th[IND * 128 + tid];
    __syncthreads();

    const int lane  = tid & 63;
    const int w     = tid >> 6;
    const int r31   = lane & 31;
    const int khalf = lane >> 5;
    const int hb    = (w >> 1) * 64;
    const int xb    = (w & 1) * 64;
    const int hA0 = hb + r31,  hA1 = hb + 32 + r31;
    const int xB0 = xb + r31,  xB1 = xb + 32 + r31;
    const int swzA0 = (hA0 & 15) << 4, swzA1 = (hA1 & 15) << 4;
    const int swzB0 = (xB0 & 15) << 4, swzB1 = (xB1 & 15) << 4;

    f32x16 acc[2][2];

    {
        const int kb = khalf * 16;
        f16x8 ah[2], al[2], bh[2], bl[2];
        ah[0] = *reinterpret_cast<const f16x8*>((const char*)sW0hi + hA0 * 32 + kb);
        ah[1] = *reinterpret_cast<const f16x8*>((const char*)sW0hi + hA1 * 32 + kb);
        al[0] = *reinterpret_cast<const f16x8*>((const char*)sW0lo + hA0 * 32 + kb);
        al[1] = *reinterpret_cast<const f16x8*>((const char*)sW0lo + hA1 * 32 + kb);
        bh[0] = *reinterpret_cast<const f16x8*>((const char*)sX0hi + xB0 * 32 + kb);
        bh[1] = *reinterpret_cast<const f16x8*>((const char*)sX0hi + xB1 * 32 + kb);
        bl[0] = *reinterpret_cast<const f16x8*>((const char*)sX0lo + xB0 * 32 + kb);
        bl[1] = *reinterpret_cast<const f16x8*>((const char*)sX0lo + xB1 * 32 + kb);
#pragma unroll
        for (int tt = 0; tt < 2; ++tt)
#pragma unroll
            for (int tx = 0; tx < 2; ++tx) {
                f32x16 a;
#pragma unroll
                for (int i = 0; i < 16; ++i) a[i] = 0.0f;
                a = MFMA(al[tt], bh[tx], a);
                a = MFMA(ah[tt], bl[tx], a);
                a = MFMA(ah[tt], bh[tx], a);
                acc[tt][tx] = a;
            }
    }

    auto epilogue = [&](const float* __restrict__ bb) {
#pragma unroll
        for (int tt = 0; tt < 2; ++tt)
#pragma unroll
            for (int tx = 0; tx < 2; ++tx) {
                const int xw  = xb + tx * 32 + r31;
                const int swz = (xw & 15) << 4;
#pragma unroll
                for (int g = 0; g < 4; ++g) {
                    const int hbase = hb + tt * 32 + g * 8 + khalf * 4;
                    f16x4 pk;
#pragma unroll
                    for (int q = 0; q < 4; ++q) {
                        const float v = acc[tt][tx][g * 4 + q] + bb[hbase + q];
                        pk[q] = (_Float16)(1.0f - 2.0f * __builtin_amdgcn_rcpf(
                            __builtin_amdgcn_exp2f(v * 2.8853900817779268f) + 1.0f));
                    }
                    *reinterpret_cast<f16x4*>((char*)sH + xw * 256 + ((hbase * 2) ^ swz)) = pk;
                }
            }
    };

    for (int l = 0; l < 3; ++l) {
        __syncthreads();
        const float* __restrict__ wsrc = th + 2176 + l * 16512;
#pragma unroll
        for (int j = 0; j < 16; ++j) {
            const int flat = j * 1024 + tid * 4;
            const int hrow = flat >> 7;
            const int o    = flat & 127;
            const float a0 = wsrc[flat], a1 = wsrc[flat + 1], a2 = wsrc[flat + 2], a3 = wsrc[flat + 3];
            _Float16 h0 = (_Float16)a0, h1 = (_Float16)a1, h2 = (_Float16)a2, h3 = (_Float16)a3;
            f16x4 ph = {h0, h1, h2, h3};
            f16x4 pl = {(_Float16)(a0 - (float)h0), (_Float16)(a1 - (float)h1),
                        (_Float16)(a2 - (float)h2), (_Float16)(a3 - (float)h3)};
            const int boff = hrow * 256 + ((o * 2) ^ ((hrow & 15) << 4));
            *reinterpret_cast<f16x4*>((char*)sWhi + boff) = ph;
            *reinterpret_cast<f16x4*>((char*)sWlo + boff) = pl;
        }
        if (tid < 128) sB[(l + 1) & 1][tid] = wsrc[128 * 128 + tid];
        if (l == 2) {
            if (tid < 128) sWl[tid] = th[51712 + tid];
            if (tid == 128) sWl[128] = th[51840];
        }

        epilogue(sB[l & 1]);
        __syncthreads();

#pragma unroll
        for (int tt = 0; tt < 2; ++tt)
#pragma unroll
            for (int tx = 0; tx < 2; ++tx)
#pragma unroll
                for (int i = 0; i < 16; ++i) acc[tt][tx][i] = 0.0f;
#pragma unroll
        for (int kc = 0; kc < 8; ++kc) {
            const int kb = kc * 32 + khalf * 16;
            f16x8 ah[2], al[2], bv[2];
            ah[0] = *reinterpret_cast<const f16x8*>((const char*)sWhi + hA0 * 256 + (kb ^ swzA0));
            ah[1] = *reinterpret_cast<const f16x8*>((const char*)sWhi + hA1 * 256 + (kb ^ swzA1));
            al[0] = *reinterpret_cast<const f16x8*>((const char*)sWlo + hA0 * 256 + (kb ^ swzA0));
            al[1] = *reinterpret_cast<const f16x8*>((const char*)sWlo + hA1 * 256 + (kb ^ swzA1));
            bv[0] = *reinterpret_cast<const f16x8*>((const char*)sH   + xB0 * 256 + (kb ^ swzB0));
            bv[1] = *reinterpret_cast<const f16x8*>((const char*)sH   + xB1 * 256 + (kb ^ swzB1));
#pragma unroll
            for (int tt = 0; tt < 2; ++tt)
#pragma unroll
                for (int tx = 0; tx < 2; ++tx) {
                    acc[tt][tx] = MFMA(al[tt], bv[tx], acc[tt][tx]);
                    acc[tt][tx] = MFMA(ah[tt], bv[tx], acc[tt][tx]);
                }
        }
    }

    __syncthreads();
    epilogue(sB[1]);
    __syncthreads();

    if (tid < 128) {
        const int r   = tid;
        const int swz = (r & 15) << 4;
        float s = 0.0f;
#pragma unroll
        for (int c = 0; c < 16; ++c) {
            const int hc = (c + r) & 15;
            const f16x8 hv = *reinterpret_cast<const f16x8*>(
                (const char*)sH + r * 256 + ((hc * 16) ^ swz));
#pragma unroll
            for (int q = 0; q < 8; ++q) s += (float)hv[q] * sWl[hc * 8 + q];
        }
        out[(size_t)t * 4096 + (size_t)xt * 128 + r] = s + sWl[128];
    }
}

extern "C" void kernel_launch(void* const* d_in, const int* in_sizes, int n_in,
                              void* d_out, int out_size, void* d_ws, size_t ws_size,
                              hipStream_t stream)
{
    const float* x     = (const float*)d_in[0];
    const float* theta = (const float*)d_in[1];
    float* out = (float*)d_out;

    if (ws_size >= (size_t)WS_TOTAL) {
        prep_kernel<<<dim3(3280), dim3(256), 0, stream>>>(theta, x, (char*)d_ws);
        mlp_main<<<dim3(1024), dim3(THREADS), 0, stream>>>((const char*)d_ws, out);
    } else {
        mlp_kernel_fb<<<dim3(4096), dim3(256), 0, stream>>>(x, theta, out);
    }
}

// Round 11
// 91.688 us; speedup vs baseline: 2.0419x; 1.0945x over previous
//
#include <hip/hip_runtime.h>

// Batched MLP, round 11: 2-tile group pipeline. Each layer = group0 (tiles
// 0,1) then group1 (tiles 2,3) whose MFMAs are INTERLEAVED in program order
// with the tanh+pack of group0 (true-dependency-free), so one in-order wave
// feeds VALU(trans) and MFMA/LDS pipes simultaneously. Acc live-set 48 AGPR,
// frag triple-buffer FA/FB/FC 48 VGPR -> ~120 regs, 16 waves/CU kept.
// Numerics identical to r10 (absmax 0.578): prescaled W/b (2*log2e), hi/lo
// layer 0, f16 hidden W, tanh = 1 - 2*rcp(1+exp2(z)), RTZ pack, permlane32.

#define IND      16
#define THREADS  1024
#define PARAMS   51841
#define SCALE    2.8853900817779268f   // 2*log2(e)

#define WS_W0    12582912                  // [0,WS_W0): 128*3 hidden W images
#define WS_SC    (WS_W0 + 128 * 8192)      // per-t W0 frag images (hi|lo)
#define WS_X     (WS_SC + 128 * 4096)      // per-t scalar blocks
#define WS_XLO   (WS_X + 131072)           // x hi rows then lo rows
#define WS_TOTAL (WS_X + 262144)           // 14,417,920

// per-t scalar block (f32): +0 b0s(128) | +128 b1..3s(384) | +512 wl(128) | +640 bl

#define LDS_B    98304                      // 3 W images below
#define LDS_WL   (LDS_B + 1536)
#define LDS_SZ   (LDS_B + 2064)

typedef _Float16 f16x8 __attribute__((ext_vector_type(8)));
typedef _Float16 f16x4 __attribute__((ext_vector_type(4)));
typedef float    f32x16 __attribute__((ext_vector_type(16)));
typedef float    f32x4v __attribute__((ext_vector_type(4)));
typedef unsigned u32x2  __attribute__((ext_vector_type(2)));

union U4 { unsigned u[4]; f16x8 v; };

// z PRE-SCALED by 2*log2(e): tanh = 1 - 2*rcp(1 + exp2(z)); saturates right.
__device__ __forceinline__ unsigned tanh2pk(float z0, float z1) {
    const float e0 = __builtin_amdgcn_exp2f(z0);
    const float e1 = __builtin_amdgcn_exp2f(z1);
    const float y0 = __builtin_fmaf(__builtin_amdgcn_rcpf(1.0f + e0), -2.0f, 1.0f);
    const float y1 = __builtin_fmaf(__builtin_amdgcn_rcpf(1.0f + e1), -2.0f, 1.0f);
    return __builtin_bit_cast(unsigned, __builtin_amdgcn_cvt_pkrtz(y0, y1));
}

#define MFMA(A, B, C) __builtin_amdgcn_mfma_f32_32x32x16_f16((A), (B), (C), 0, 0, 0)

__device__ __forceinline__ void gload16(const void* g, void* l) {
    __builtin_amdgcn_global_load_lds(
        (const __attribute__((address_space(1))) void*)g,
        (__attribute__((address_space(3))) void*)l, 16, 0, 0);
}

__device__ __forceinline__ void conv8(const float* __restrict__ s, char* hidst,
                                      char* lodst, float scale) {
    float v[8];
    *reinterpret_cast<float4*>(v)     = *reinterpret_cast<const float4*>(s);
    *reinterpret_cast<float4*>(v + 4) = *reinterpret_cast<const float4*>(s + 4);
    f16x8 hi, lo;
#pragma unroll
    for (int i = 0; i < 8; ++i) {
        const float sv = v[i] * scale;
        hi[i] = (_Float16)sv;
        lo[i] = (_Float16)(sv - (float)hi[i]);
    }
    *reinterpret_cast<f16x8*>(hidst) = hi;
    *reinterpret_cast<f16x8*>(lodst) = lo;
}

// ---------------------------------------------------------------------------
// prep (identical to round 10)
// ---------------------------------------------------------------------------
__global__ __launch_bounds__(256)
void prep_kernel(const float* __restrict__ theta, const float* __restrict__ xin,
                 char* __restrict__ ws)
{
    const int b = blockIdx.x, tid = threadIdx.x;
    if (b < 3072) {
        const int t = b / 24, rem = b % 24, li = rem >> 3, hblk = rem & 7;
        const int h  = hblk * 16 + (tid >> 4);
        const int kc = (tid >> 1) & 7, kh = tid & 1;
        const float* src = theta + (size_t)t * PARAMS + 2176 + li * 16512
                         + h * 128 + kc * 16 + kh * 8;
        float v[8];
        *reinterpret_cast<float4*>(v)     = *reinterpret_cast<const float4*>(src);
        *reinterpret_cast<float4*>(v + 4) = *reinterpret_cast<const float4*>(src + 4);
        f16x8 p;
#pragma unroll
        for (int i = 0; i < 8; ++i) p[i] = (_Float16)(v[i] * SCALE);
        char* img = ws + ((size_t)(t * 3 + li) << 15);
        *reinterpret_cast<f16x8*>(img + ((h >> 5) * 8 + kc) * 1024
                                      + (kh * 32 + (h & 31)) * 16) = p;
    } else if (b < 3136) {
        const int gid = (b - 3072) * 256 + tid;
        const int t = gid >> 7, h = gid & 127;
        const float* src = theta + (size_t)t * PARAMS + h * IND;
        char* dst = ws + WS_W0 + (size_t)t * 8192 + h * 32;
        conv8(src,     dst,      dst + 4096,      SCALE);
        conv8(src + 8, dst + 16, dst + 4096 + 16, SCALE);
    } else if (b < 3264) {
        const int t = b - 3136;
        const float* th = theta + (size_t)t * PARAMS;
        float* base = reinterpret_cast<float*>(ws + WS_SC + (size_t)t * 4096);
        if (tid < 128) base[tid] = SCALE * th[2048 + tid];                 // b0s
        for (int k = tid; k < 384; k += 256)                               // b1..3s
            base[128 + k] = SCALE * th[2176 + (k >> 7) * 16512 + 16384 + (k & 127)];
        if (tid < 128) base[512 + tid] = th[51712 + tid];                  // wl
        if (tid == 0)  base[640] = th[51840];                              // bl
    } else {
        const int row = (b - 3264) * 256 + tid;
        const float* src = xin + (size_t)row * IND;
        char* hid = ws + WS_X   + (size_t)row * 32;
        char* lod = ws + WS_XLO + (size_t)row * 32;
        conv8(src,     hid,      lod,      1.0f);
        conv8(src + 8, hid + 16, lod + 16, 1.0f);
    }
}

// ---------------------------------------------------------------------------
// main: 1024 threads (16 waves, 4/SIMD), 1 block/CU, ONE barrier,
// 2-tile-group software pipeline inside each layer.
// ---------------------------------------------------------------------------
__global__ __launch_bounds__(THREADS, 4)
void mlp_main(const char* __restrict__ ws, float* __restrict__ out)
{
    __shared__ __align__(16) char sL[LDS_SZ];

    const int tid = threadIdx.x, bid = blockIdx.x;
    const int sw  = (bid & 7) * 128 + (bid >> 3);   // XCD-bijective (1024%8==0)
    const int t   = sw >> 3, xt = sw & 7;           // xt: 512-x tile index
    const int lane = tid & 63, w = tid >> 6, r31 = lane & 31, khalf = lane >> 5;
    const int bpa  = (lane ^ 32) << 2;
    (void)bpa;

    const float* __restrict__ wsc = reinterpret_cast<const float*>(
        ws + WS_SC + (size_t)t * 4096);

    // ---- issue stage of W1|W2|W3 (96KB contiguous) -> LDS[0,96K) ----
    {
        const char* img = ws + ((size_t)(t * 3) << 15);
#pragma unroll
        for (int c = 0; c < 6; ++c) {
            const int o = (c * 1024 + tid) * 16;
            gload16(img + o, sL + o);
        }
    }
    // ---- stage scaled b1..3 + wl + bl tables ----
    if (tid < 513)
        *reinterpret_cast<float*>(sL + LDS_B + tid * 4) = wsc[128 + tid];

    // ------------------------ helpers ------------------------
    auto asm2 = [&](const unsigned* P0, const unsigned* P1, f16x8* dst) {
#pragma unroll
        for (int j = 0; j < 2; ++j) {
#if __has_builtin(__builtin_amdgcn_permlane32_swap)
            const u32x2 r0 = __builtin_amdgcn_permlane32_swap(
                P0[2 * j], P0[2 * j + 1], false, false);
            const u32x2 r1 = __builtin_amdgcn_permlane32_swap(
                P1[2 * j], P1[2 * j + 1], false, false);
            U4 u;
            u.u[0] = r0[0]; u.u[1] = r1[0]; u.u[2] = r0[1]; u.u[3] = r1[1];
#else
            const unsigned s0 = khalf ? P0[2 * j] : P0[2 * j + 1];
            const unsigned s1 = khalf ? P1[2 * j] : P1[2 * j + 1];
            const unsigned q0 = (unsigned)__builtin_amdgcn_ds_bpermute(bpa, (int)s0);
            const unsigned q1 = (unsigned)__builtin_amdgcn_ds_bpermute(bpa, (int)s1);
            U4 u;
            u.u[0] = khalf ? q0 : P0[2 * j];
            u.u[1] = khalf ? q1 : P1[2 * j];
            u.u[2] = khalf ? P0[2 * j + 1] : q0;
            u.u[3] = khalf ? P1[2 * j + 1] : q1;
#endif
            dst[j] = u.v;
        }
    };
    auto pack2 = [&](const f32x16& a, f16x8* dst) {   // full pack of one tile
        unsigned P0[4], P1[4];
#pragma unroll
        for (int g = 0; g < 4; ++g) {
            P0[g] = tanh2pk(a[4 * g + 0], a[4 * g + 1]);
            P1[g] = tanh2pk(a[4 * g + 2], a[4 * g + 3]);
        }
        asm2(P0, P1, dst);
    };
    auto biasin = [&](f32x16& a, const char* btab, int tt) {
#pragma unroll
        for (int g = 0; g < 4; ++g) {
            const f32x4v bv = *reinterpret_cast<const f32x4v*>(
                btab + (tt * 32 + g * 8) * 4 + khalf * 16);
            a[4 * g + 0] = bv[0]; a[4 * g + 1] = bv[1];
            a[4 * g + 2] = bv[2]; a[4 * g + 3] = bv[3];
        }
    };
    auto mfma8 = [&](f32x16& a, const char* wimg, int tt,
                     const f16x8* in0, const f16x8* in1) {
#pragma unroll
        for (int kc = 0; kc < 8; ++kc) {
            const f16x8 av = *reinterpret_cast<const f16x8*>(
                wimg + (tt * 8 + kc) * 1024 + lane * 16);
            a = MFMA(av, kc < 4 ? in0[kc] : in1[kc - 4], a);
        }
    };
    // tile-tt MFMAs interleaved (program order!) with tanh of src -> P arrays
    auto inter8 = [&](f32x16& a, const char* wimg, int tt,
                      const f16x8* in0, const f16x8* in1,
                      const f32x16& src, unsigned* P0, unsigned* P1) {
#pragma unroll
        for (int kc = 0; kc < 8; ++kc) {
            const f16x8 av = *reinterpret_cast<const f16x8*>(
                wimg + (tt * 8 + kc) * 1024 + lane * 16);
            a = MFMA(av, kc < 4 ? in0[kc] : in1[kc - 4], a);
            if (!(kc & 1)) {
                const int g = kc >> 1;
                P0[g] = tanh2pk(src[4 * g + 0], src[4 * g + 1]);
                P1[g] = tanh2pk(src[4 * g + 2], src[4 * g + 3]);
            }
        }
    };
    // tile-tt MFMAs interleaved with the final dot of src tile tts
    auto inter8f = [&](f32x16& a, const char* wimg, int tt,
                       const f16x8* in0, const f16x8* in1,
                       const f32x16& src, int tts, float& s) {
#pragma unroll
        for (int kc = 0; kc < 8; ++kc) {
            const f16x8 av = *reinterpret_cast<const f16x8*>(
                wimg + (tt * 8 + kc) * 1024 + lane * 16);
            a = MFMA(av, kc < 4 ? in0[kc] : in1[kc - 4], a);
            if (!(kc & 1)) {
                const int g = kc >> 1;
                const f32x4v wv = *reinterpret_cast<const f32x4v*>(
                    sL + LDS_WL + (tts * 32 + g * 8) * 4 + khalf * 16);
#pragma unroll
                for (int q = 0; q < 4; ++q) {
                    const float z = src[4 * g + q];
                    const float e = __builtin_amdgcn_exp2f(z);
                    const float y = __builtin_fmaf(
                        __builtin_amdgcn_rcpf(1.0f + e), -2.0f, 1.0f);
                    s = __builtin_fmaf(y, wv[q], s);
                }
            }
        }
    };
    auto fdot = [&](const f32x16& a, int tt, float& s) {  // serial final dot
#pragma unroll
        for (int g = 0; g < 4; ++g) {
            const f32x4v wv = *reinterpret_cast<const f32x4v*>(
                sL + LDS_WL + (tt * 32 + g * 8) * 4 + khalf * 16);
#pragma unroll
            for (int q = 0; q < 4; ++q) {
                const float z = a[4 * g + q];
                const float e = __builtin_amdgcn_exp2f(z);
                const float y = __builtin_fmaf(
                    __builtin_amdgcn_rcpf(1.0f + e), -2.0f, 1.0f);
                s = __builtin_fmaf(y, wv[q], s);
            }
        }
    };

    // ------------------------ layer 0 (group-wise, 32-AGPR live) ----------
    f16x8 FA[4], FB[4], FC[4];
    {
        const char* w0i = ws + WS_W0 + (size_t)t * 8192;
        const int ro = r31 * 32 + khalf * 16;
        const int xrow = (xt * 512 + w * 32) * 32;
        const f16x8 B0h = *reinterpret_cast<const f16x8*>(ws + WS_X   + xrow + ro);
        const f16x8 B0l = *reinterpret_cast<const f16x8*>(ws + WS_XLO + xrow + ro);
        auto l0tile = [&](f32x16& a, int tt) {
#pragma unroll
            for (int g = 0; g < 4; ++g) {
                const f32x4v bv = *reinterpret_cast<const f32x4v*>(
                    wsc + tt * 32 + g * 8 + khalf * 4);
                a[4 * g + 0] = bv[0]; a[4 * g + 1] = bv[1];
                a[4 * g + 2] = bv[2]; a[4 * g + 3] = bv[3];
            }
            const f16x8 Ah = *reinterpret_cast<const f16x8*>(w0i + tt * 1024 + ro);
            const f16x8 Al = *reinterpret_cast<const f16x8*>(w0i + 4096 + tt * 1024 + ro);
            a = MFMA(Al, B0h, a);
            a = MFMA(Ah, B0l, a);
            a = MFMA(Ah, B0h, a);
        };
        f32x16 c0, c1;
        l0tile(c0, 0); l0tile(c1, 1);
        pack2(c0, &FA[0]); pack2(c1, &FA[2]);
        l0tile(c0, 2); l0tile(c1, 3);
        pack2(c0, &FB[0]); pack2(c1, &FB[2]);
    }
    __syncthreads();   // THE ONLY BARRIER: W1..W3 + tables visible

    // ------------------------ hidden layer (pipelined groups) -------------
    auto hidden = [&](const char* wimg, const char* btab,
                      f16x8* in0, f16x8* in1, f16x8* out0) {
        f32x16 c0, c1, c2, c3;
        __builtin_amdgcn_s_setprio(1);
        biasin(c0, btab, 0); mfma8(c0, wimg, 0, in0, in1);
        biasin(c1, btab, 1); mfma8(c1, wimg, 1, in0, in1);
        {
            unsigned P0[4], P1[4];
            biasin(c2, btab, 2);
            inter8(c2, wimg, 2, in0, in1, c0, P0, P1);   // pack(c0) ∥ MFMA(c2)
            asm2(P0, P1, out0 + 0);                      // kc0,1
        }
        {
            unsigned P0[4], P1[4];
            biasin(c3, btab, 3);
            inter8(c3, wimg, 3, in0, in1, c1, P0, P1);   // pack(c1) ∥ MFMA(c3)
            asm2(P0, P1, out0 + 2);                      // kc2,3
        }
        __builtin_amdgcn_s_setprio(0);
        pack2(c2, in1 + 0);                              // kc4,5 (in1 dead)
        pack2(c3, in1 + 2);                              // kc6,7
    };

    hidden(sL,         sL + LDS_B,        FA, FB, FC);   // L1: in(FA,FB)->out(FC,FB)
    hidden(sL + 32768, sL + LDS_B + 512,  FC, FB, FA);   // L2: in(FC,FB)->out(FA,FB)

    // ------------------------ final layer (pipelined) ---------------------
    float s = 0.0f;
    {
        const char* wimg = sL + 65536;
        const char* btab = sL + LDS_B + 1024;
        f32x16 c0, c1, c2, c3;
        __builtin_amdgcn_s_setprio(1);
        biasin(c0, btab, 0); mfma8(c0, wimg, 0, FA, FB);
        biasin(c1, btab, 1); mfma8(c1, wimg, 1, FA, FB);
        biasin(c2, btab, 2); inter8f(c2, wimg, 2, FA, FB, c0, 0, s);
        biasin(c3, btab, 3); inter8f(c3, wimg, 3, FA, FB, c1, 1, s);
        __builtin_amdgcn_s_setprio(0);
        fdot(c2, 2, s);
        fdot(c3, 3, s);
    }
    const float sp = __builtin_bit_cast(float,
        __builtin_amdgcn_ds_bpermute(bpa, __builtin_bit_cast(int, s)));
    const float res = s + sp + *reinterpret_cast<const float*>(sL + LDS_WL + 512);
    if (!khalf) out[(size_t)t * 4096 + xt * 512 + w * 32 + r31] = res;
}

// ---------------------------------------------------------------------------
// Fallback (self-contained, known-good round-1 kernel) if ws is too small.
// ---------------------------------------------------------------------------
__global__ __launch_bounds__(256, 1)
void mlp_kernel_fb(const float* __restrict__ xin,
                   const float* __restrict__ theta,
                   float* __restrict__ out)
{
    __shared__ __align__(16) _Float16 sH   [128 * 128];
    __shared__ __align__(16) _Float16 sWhi [128 * 128];
    __shared__ __align__(16) _Float16 sWlo [128 * 128];
    __shared__ __align__(16) _Float16 sX0hi[128 * IND];
    __shared__ __align__(16) _Float16 sX0lo[128 * IND];
    __shared__ __align__(16) _Float16 sW0hi[128 * IND];
    __shared__ __align__(16) _Float16 sW0lo[128 * IND];
    __shared__ float sB[2][128];
    __shared__ float sWl[129];

    const int tid = threadIdx.x;
    const int bid = blockIdx.x;
    const int sw  = (bid & 7) * 512 + (bid >> 3);
    const int t   = sw >> 5;
    const int xt  = sw & 31;
    const float* __restrict__ th = theta + (size_t)t * PARAMS;
    const float* __restrict__ xg = xin   + (size_t)xt * (128 * IND);

#pragma unroll
    for (int j = 0; j < 2; ++j) {
        const int flat = j * 1024 + tid * 4;
        const float4 v = *reinterpret_cast<const float4*>(xg + flat);
        _Float16 h0 = (_Float16)v.x, h1 = (_Float16)v.y, h2 = (_Float16)v.z, h3 = (_Float16)v.w;
        f16x4 ph = {h0, h1, h2, h3};
        f16x4 pl = {(_Float16)(v.x - (float)h0), (_Float16)(v.y - (float)h1),
                    (_Float16)(v.z - (float)h2), (_Float16)(v.w - (float)h3)};
        *reinterpret_cast<f16x4*>(&sX0hi[flat]) = ph;
        *reinterpret_cast<f16x4*>(&sX0lo[flat]) = pl;
    }
#pragma unroll
    for (int j = 0; j < 2; ++j) {
        const int flat = j * 1024 + tid * 4;
        const float a0 = th[flat], a1 = th[flat + 1], a2 = th[flat + 2], a3 = th[flat + 3];
        _Float16 h0 = (_Float16)a0, h1 = (_Float16)a1, h2 = (_Float16)a2, h3 = (_Float16)a3;
        f16x4 ph = {h0, h1, h2, h3};
        f16x4 pl = {(_Float16)(a0 - (float)h0), (_Float16)(a1 - (float)h1),
                    (_Float16)(a2 - (float)h2), (_Float16)(a3 - (float)h3)};
        *reinterpret_cast<f16x4*>(&sW0hi[flat]) = ph;
        *reinterpret_cast<f16x4*>(&sW0lo[flat]) = pl;
    }
    if (tid < 128) sB[0][tid] = th[IND * 128 + tid];
    __syncthreads();

    const int lane  = tid & 63;
    const int w     = tid >> 6;
    const int r31   = lane & 31;
    const int khalf = lane >> 5;
    const int hb    = (w >> 1) * 64;
    const int xb    = (w & 1) * 64;
    const int hA0 = hb + r31,  hA1 = hb + 32 + r31;
    const int xB0 = xb + r31,  xB1 = xb + 32 + r31;
    const int swzA0 = (hA0 & 15) << 4, swzA1 = (hA1 & 15) << 4;
    const int swzB0 = (xB0 & 15) << 4, swzB1 = (xB1 & 15) << 4;

    f32x16 acc[2][2];

    {
        const int kb = khalf * 16;
        f16x8 ah[2], al[2], bh[2], bl[2];
        ah[0] = *reinterpret_cast<const f16x8*>((const char*)sW0hi + hA0 * 32 + kb);
        ah[1] = *reinterpret_cast<const f16x8*>((const char*)sW0hi + hA1 * 32 + kb);
        al[0] = *reinterpret_cast<const f16x8*>((const char*)sW0lo + hA0 * 32 + kb);
        al[1] = *reinterpret_cast<const f16x8*>((const char*)sW0lo + hA1 * 32 + kb);
        bh[0] = *reinterpret_cast<const f16x8*>((const char*)sX0hi + xB0 * 32 + kb);
        bh[1] = *reinterpret_cast<const f16x8*>((const char*)sX0hi + xB1 * 32 + kb);
        bl[0] = *reinterpret_cast<const f16x8*>((const char*)sX0lo + xB0 * 32 + kb);
        bl[1] = *reinterpret_cast<const f16x8*>((const char*)sX0lo + xB1 * 32 + kb);
#pragma unroll
        for (int tt = 0; tt < 2; ++tt)
#pragma unroll
            for (int tx = 0; tx < 2; ++tx) {
                f32x16 a;
#pragma unroll
                for (int i = 0; i < 16; ++i) a[i] = 0.0f;
                a = MFMA(al[tt], bh[tx], a);
                a = MFMA(ah[tt], bl[tx], a);
                a = MFMA(ah[tt], bh[tx], a);
                acc[tt][tx] = a;
            }
    }

    auto epilogue = [&](const float* __restrict__ bb) {
#pragma unroll
        for (int tt = 0; tt < 2; ++tt)
#pragma unroll
            for (int tx = 0; tx < 2; ++tx) {
                const int xw  = xb + tx * 32 + r31;
                const int swz = (xw & 15) << 4;
#pragma unroll
                for (int g = 0; g < 4; ++g) {
                    const int hbase = hb + tt * 32 + g * 8 + khalf * 4;
                    f16x4 pk;
#pragma unroll
                    for (int q = 0; q < 4; ++q) {
                        const float v = acc[tt][tx][g * 4 + q] + bb[hbase + q];
                        pk[q] = (_Float16)(1.0f - 2.0f * __builtin_amdgcn_rcpf(
                            __builtin_amdgcn_exp2f(v * 2.8853900817779268f) + 1.0f));
                    }
                    *reinterpret_cast<f16x4*>((char*)sH + xw * 256 + ((hbase * 2) ^ swz)) = pk;
                }
            }
    };

    for (int l = 0; l < 3; ++l) {
        __syncthreads();
        const float* __restrict__ wsrc = th + 2176 + l * 16512;
#pragma unroll
        for (int j = 0; j < 16; ++j) {
            const int flat = j * 1024 + tid * 4;
            const int hrow = flat >> 7;
            const int o    = flat & 127;
            const float a0 = wsrc[flat], a1 = wsrc[flat + 1], a2 = wsrc[flat + 2], a3 = wsrc[flat + 3];
            _Float16 h0 = (_Float16)a0, h1 = (_Float16)a1, h2 = (_Float16)a2, h3 = (_Float16)a3;
            f16x4 ph = {h0, h1, h2, h3};
            f16x4 pl = {(_Float16)(a0 - (float)h0), (_Float16)(a1 - (float)h1),
                        (_Float16)(a2 - (float)h2), (_Float16)(a3 - (float)h3)};
            const int boff = hrow * 256 + ((o * 2) ^ ((hrow & 15) << 4));
            *reinterpret_cast<f16x4*>((char*)sWhi + boff) = ph;
            *reinterpret_cast<f16x4*>((char*)sWlo + boff) = pl;
        }
        if (tid < 128) sB[(l + 1) & 1][tid] = wsrc[128 * 128 + tid];
        if (l == 2) {
            if (tid < 128) sWl[tid] = th[51712 + tid];
            if (tid == 128) sWl[128] = th[51840];
        }

        epilogue(sB[l & 1]);
        __syncthreads();

#pragma unroll
        for (int tt = 0; tt < 2; ++tt)
#pragma unroll
            for (int tx = 0; tx < 2; ++tx)
#pragma unroll
                for (int i = 0; i < 16; ++i) acc[tt][tx][i] = 0.0f;
#pragma unroll
        for (int kc = 0; kc < 8; ++kc) {
            const int kb = kc * 32 + khalf * 16;
            f16x8 ah[2], al[2], bv[2];
            ah[0] = *reinterpret_cast<const f16x8*>((const char*)sWhi + hA0 * 256 + (kb ^ swzA0));
            ah[1] = *reinterpret_cast<const f16x8*>((const char*)sWhi + hA1 * 256 + (kb ^ swzA1));
            al[0] = *reinterpret_cast<const f16x8*>((const char*)sWlo + hA0 * 256 + (kb ^ swzA0));
            al[1] = *reinterpret_cast<const f16x8*>((const char*)sWlo + hA1 * 256 + (kb ^ swzA1));
            bv[0] = *reinterpret_cast<const f16x8*>((const char*)sH   + xB0 * 256 + (kb ^ swzB0));
            bv[1] = *reinterpret_cast<const f16x8*>((const char*)sH   + xB1 * 256 + (kb ^ swzB1));
#pragma unroll
            for (int tt = 0; tt < 2; ++tt)
#pragma unroll
                for (int tx = 0; tx < 2; ++tx) {
                    acc[tt][tx] = MFMA(al[tt], bv[tx], acc[tt][tx]);
                    acc[tt][tx] = MFMA(ah[tt], bv[tx], acc[tt][tx]);
                }
        }
    }

    __syncthreads();
    epilogue(sB[1]);
    __syncthreads();

    if (tid < 128) {
        const int r   = tid;
        const int swz = (r & 15) << 4;
        float s = 0.0f;
#pragma unroll
        for (int c = 0; c < 16; ++c) {
            const int hc = (c + r) & 15;
            const f16x8 hv = *reinterpret_cast<const f16x8*>(
                (const char*)sH + r * 256 + ((hc * 16) ^ swz));
#pragma unroll
            for (int q = 0; q < 8; ++q) s += (float)hv[q] * sWl[hc * 8 + q];
        }
        out[(size_t)t * 4096 + (size_t)xt * 128 + r] = s + sWl[128];
    }
}

extern "C" void kernel_launch(void* const* d_in, const int* in_sizes, int n_in,
                              void* d_out, int out_size, void* d_ws, size_t ws_size,
                              hipStream_t stream)
{
    const float* x     = (const float*)d_in[0];
    const float* theta = (const float*)d_in[1];
    float* out = (float*)d_out;

    if (ws_size >= (size_t)WS_TOTAL) {
        prep_kernel<<<dim3(3280), dim3(256), 0, stream>>>(theta, x, (char*)d_ws);
        mlp_main<<<dim3(1024), dim3(THREADS), 0, stream>>>((const char*)d_ws, out);
    } else {
        mlp_kernel_fb<<<dim3(4096), dim3(256), 0, stream>>>(x, theta, out);
    }
}